// Round 1
// baseline (7355.566 us; speedup 1.0000x reference)
//
#include <hip/hip_runtime.h>
#include <math.h>

#define FDIM 4096
#define DDIM 256
#define ALPHA_R 0.001f

// ---------------- column sums: s = sum_f x[b,f,:] ----------------
__global__ void colsum_partial(const float* __restrict__ q,
                               const float* __restrict__ k,
                               const float* __restrict__ v,
                               float* __restrict__ part) {
  int chunk = blockIdx.x;   // 16
  int which = blockIdx.y;   // 3: 0=q 1=k 2=v
  int b     = blockIdx.z;   // 32
  const float* x = (which == 0) ? q : (which == 1 ? k : v);
  int d = threadIdx.x;
  int f0 = chunk * (FDIM / 16);
  const float* p = x + ((size_t)b * FDIM + f0) * DDIM + d;
  float s = 0.f;
  for (int i = 0; i < FDIM / 16; ++i) s += p[(size_t)i * DDIM];
  part[(((size_t)chunk * 3 + which) * 32 + b) * DDIM + d] = s;
}

__global__ void colsum_reduce(const float* __restrict__ part,
                              float* __restrict__ svec) {
  int which = blockIdx.x; int b = blockIdx.y; int d = threadIdx.x;
  float s = 0.f;
  for (int c = 0; c < 16; ++c)
    s += part[(((size_t)c * 3 + which) * 32 + b) * DDIM + d];
  svec[((size_t)which * 32 + b) * DDIM + d] = s;
}

// ---------------- batched Gram: G[b][0]=k^T k, G[b][1]=k^T v ----------------
// 64x64 tile per block, 4x4 per thread, chunked f32 accumulation for accuracy.
__global__ __launch_bounds__(256) void gram64(const float* __restrict__ kk,
                                              const float* __restrict__ vv,
                                              float* __restrict__ G) {
  int tile = blockIdx.x;      // 16 = 4x4
  int which = blockIdx.y;     // 2
  int b = blockIdx.z;         // 32
  int tm = tile >> 2, tn = tile & 3;
  const float* X = kk + (size_t)b * FDIM * DDIM;
  const float* Y = (which ? vv : kk) + (size_t)b * FDIM * DDIM;
  int mBase = tm * 64, nBase = tn * 64;
  __shared__ __align__(16) float Xs[16][64];
  __shared__ __align__(16) float Ys[16][64];
  int tid = threadIdx.x;
  int row = tid >> 4, col4 = tid & 15;   // load mapping
  int ty = tid >> 4, tx = tid & 15;      // compute mapping
  float mac[4][4], cac[4][4];
#pragma unroll
  for (int i = 0; i < 4; i++)
#pragma unroll
    for (int j = 0; j < 4; j++) { mac[i][j] = 0.f; cac[i][j] = 0.f; }

  for (int it = 0; it < FDIM / 16; ++it) {
    int f0 = it * 16;
    const float4 a4 = *(const float4*)(X + (size_t)(f0 + row) * DDIM + mBase + col4 * 4);
    const float4 b4 = *(const float4*)(Y + (size_t)(f0 + row) * DDIM + nBase + col4 * 4);
    __syncthreads();
    *(float4*)&Xs[row][col4 * 4] = a4;
    *(float4*)&Ys[row][col4 * 4] = b4;
    __syncthreads();
#pragma unroll
    for (int kstep = 0; kstep < 16; ++kstep) {
      float4 a = *(const float4*)&Xs[kstep][ty * 4];
      float4 bb = *(const float4*)&Ys[kstep][tx * 4];
      float av[4] = {a.x, a.y, a.z, a.w};
      float bvv[4] = {bb.x, bb.y, bb.z, bb.w};
#pragma unroll
      for (int i = 0; i < 4; i++)
#pragma unroll
        for (int j = 0; j < 4; j++)
          cac[i][j] = fmaf(av[i], bvv[j], cac[i][j]);
    }
    if ((it & 7) == 7) {   // flush every 128 f -> keeps diagonal drift ~5e-3
#pragma unroll
      for (int i = 0; i < 4; i++)
#pragma unroll
        for (int j = 0; j < 4; j++) { mac[i][j] += cac[i][j]; cac[i][j] = 0.f; }
    }
  }
  float* C = G + (((size_t)b * 2 + which) * DDIM) * DDIM;
#pragma unroll
  for (int i = 0; i < 4; i++) {
    float4 o = make_float4(mac[i][0], mac[i][1], mac[i][2], mac[i][3]);
    *(float4*)(C + (size_t)(mBase + ty * 4 + i) * DDIM + nBase + tx * 4) = o;
  }
}

// ---------------- small vectors: uk=Wk sk, uv=Wv sv, qsum=Wq sq + F bq ------
__global__ void smallvec(const float* __restrict__ Wq, const float* __restrict__ bq,
                         const float* __restrict__ Wk, const float* __restrict__ Wv,
                         const float* __restrict__ svec, float* __restrict__ uvec) {
  int b = blockIdx.x; int d = threadIdx.x;
  __shared__ float sq[256], sk[256], sv[256];
  sq[d] = svec[((size_t)0 * 32 + b) * DDIM + d];
  sk[d] = svec[((size_t)1 * 32 + b) * DDIM + d];
  sv[d] = svec[((size_t)2 * 32 + b) * DDIM + d];
  __syncthreads();
  float uk = 0.f, uv = 0.f, uq = 0.f;
  for (int j = 0; j < 256; j += 4) {
    float4 wk4 = *(const float4*)(Wk + (size_t)d * DDIM + j);
    float4 wv4 = *(const float4*)(Wv + (size_t)d * DDIM + j);
    float4 wq4 = *(const float4*)(Wq + (size_t)d * DDIM + j);
    uk += wk4.x * sk[j] + wk4.y * sk[j + 1] + wk4.z * sk[j + 2] + wk4.w * sk[j + 3];
    uv += wv4.x * sv[j] + wv4.y * sv[j + 1] + wv4.z * sv[j + 2] + wv4.w * sv[j + 3];
    uq += wq4.x * sq[j] + wq4.y * sq[j + 1] + wq4.z * sq[j + 2] + wq4.w * sq[j + 3];
  }
  uvec[((size_t)0 * 32 + b) * DDIM + d] = uk;
  uvec[((size_t)1 * 32 + b) * DDIM + d] = uv;
  uvec[((size_t)2 * 32 + b) * DDIM + d] = uq + 4096.f * bq[d];
}

// ---------------- T[b][w] = Wk @ G[b][w]  (nn GEMM, 256^3) ----------------
__global__ __launch_bounds__(256) void gemm_pass1(const float* __restrict__ Wk,
                                                  const float* __restrict__ G,
                                                  float* __restrict__ T) {
  int tile = blockIdx.x, w = blockIdx.y, b = blockIdx.z;
  int tm = tile >> 2, tn = tile & 3;
  const float* A = Wk;
  const float* B = G + ((size_t)b * 2 + w) * 65536;
  float* C = T + ((size_t)b * 2 + w) * 65536;
  __shared__ __align__(16) float As[16][64];
  __shared__ __align__(16) float Bs[16][64];
  int tid = threadIdx.x;
  int ty = tid >> 4, tx = tid & 15;
  int am = tid & 63, ak4 = tid >> 6;
  int brow = tid >> 4, bcol4 = tid & 15;
  int mBase = tm * 64, nBase = tn * 64;
  float acc[4][4];
#pragma unroll
  for (int i = 0; i < 4; i++)
#pragma unroll
    for (int j = 0; j < 4; j++) acc[i][j] = 0.f;
  for (int k0 = 0; k0 < 256; k0 += 16) {
    float4 a = *(const float4*)(A + (size_t)(mBase + am) * DDIM + k0 + ak4 * 4);
    float4 bb = *(const float4*)(B + (size_t)(k0 + brow) * DDIM + nBase + bcol4 * 4);
    __syncthreads();
    As[ak4 * 4 + 0][am] = a.x; As[ak4 * 4 + 1][am] = a.y;
    As[ak4 * 4 + 2][am] = a.z; As[ak4 * 4 + 3][am] = a.w;
    *(float4*)&Bs[brow][bcol4 * 4] = bb;
    __syncthreads();
#pragma unroll
    for (int kstep = 0; kstep < 16; ++kstep) {
      float4 a4 = *(const float4*)&As[kstep][ty * 4];
      float4 b4 = *(const float4*)&Bs[kstep][tx * 4];
      float av[4] = {a4.x, a4.y, a4.z, a4.w};
      float bvv[4] = {b4.x, b4.y, b4.z, b4.w};
#pragma unroll
      for (int i = 0; i < 4; i++)
#pragma unroll
        for (int j = 0; j < 4; j++)
          acc[i][j] = fmaf(av[i], bvv[j], acc[i][j]);
    }
  }
#pragma unroll
  for (int i = 0; i < 4; i++) {
    float4 o = make_float4(acc[i][0], acc[i][1], acc[i][2], acc[i][3]);
    *(float4*)(C + (size_t)(mBase + ty * 4 + i) * DDIM + nBase + tx * 4) = o;
  }
}

// ---------------- S[b][w] = T[b][w] @ W^T  (nt GEMM) ----------------
__global__ __launch_bounds__(256) void gemm_pass2(const float* __restrict__ T,
                                                  const float* __restrict__ Wk,
                                                  const float* __restrict__ Wv,
                                                  float* __restrict__ S) {
  int tile = blockIdx.x, w = blockIdx.y, b = blockIdx.z;
  int tm = tile >> 2, tn = tile & 3;
  const float* A = T + ((size_t)b * 2 + w) * 65536;
  const float* W = w ? Wv : Wk;
  float* C = S + ((size_t)b * 2 + w) * 65536;
  __shared__ __align__(16) float As[16][64];
  __shared__ __align__(16) float Bs[16][64];
  int tid = threadIdx.x;
  int ty = tid >> 4, tx = tid & 15;
  int am = tid & 63, ak4 = tid >> 6;
  int mBase = tm * 64, nBase = tn * 64;
  float acc[4][4];
#pragma unroll
  for (int i = 0; i < 4; i++)
#pragma unroll
    for (int j = 0; j < 4; j++) acc[i][j] = 0.f;
  for (int k0 = 0; k0 < 256; k0 += 16) {
    float4 a = *(const float4*)(A + (size_t)(mBase + am) * DDIM + k0 + ak4 * 4);
    float4 bb = *(const float4*)(W + (size_t)(nBase + am) * DDIM + k0 + ak4 * 4);
    __syncthreads();
    As[ak4 * 4 + 0][am] = a.x; As[ak4 * 4 + 1][am] = a.y;
    As[ak4 * 4 + 2][am] = a.z; As[ak4 * 4 + 3][am] = a.w;
    Bs[ak4 * 4 + 0][am] = bb.x; Bs[ak4 * 4 + 1][am] = bb.y;
    Bs[ak4 * 4 + 2][am] = bb.z; Bs[ak4 * 4 + 3][am] = bb.w;
    __syncthreads();
#pragma unroll
    for (int kstep = 0; kstep < 16; ++kstep) {
      float4 a4 = *(const float4*)&As[kstep][ty * 4];
      float4 b4 = *(const float4*)&Bs[kstep][tx * 4];
      float av[4] = {a4.x, a4.y, a4.z, a4.w};
      float bvv[4] = {b4.x, b4.y, b4.z, b4.w};
#pragma unroll
      for (int i = 0; i < 4; i++)
#pragma unroll
        for (int j = 0; j < 4; j++)
          acc[i][j] = fmaf(av[i], bvv[j], acc[i][j]);
    }
  }
#pragma unroll
  for (int i = 0; i < 4; i++) {
    float4 o = make_float4(acc[i][0], acc[i][1], acc[i][2], acc[i][3]);
    *(float4*)(C + (size_t)(mBase + ty * 4 + i) * DDIM + nBase + tx * 4) = o;
  }
}

// ---------------- rank-1 bias terms + alpha*I ----------------
__global__ void rank1(float* __restrict__ S, const float* __restrict__ uvec,
                      const float* __restrict__ bk, const float* __restrict__ bv) {
  int d = blockIdx.x, w = blockIdx.y, b = blockIdx.z;
  int e = threadIdx.x;
  float* row = S + (((size_t)b * 2 + w) * DDIM + d) * DDIM;
  float ukd = uvec[((size_t)0 * 32 + b) * DDIM + d];
  float bkd = bk[d];
  if (w == 0) {
    float uke = uvec[((size_t)0 * 32 + b) * DDIM + e];
    float add = ukd * bk[e] + bkd * uke + 4096.f * bkd * bk[e] + ((d == e) ? ALPHA_R : 0.f);
    row[e] += add;
  } else {
    float uve = uvec[((size_t)1 * 32 + b) * DDIM + e];
    float add = ukd * bv[e] + bkd * uve + 4096.f * bkd * bv[e];
    row[e] += add;
  }
}

// ---------------- per-batch Gauss-Jordan solve: S[b][1] <- S[b][0]^-1 S[b][1]
__global__ __launch_bounds__(1024) void gj_solve(float* __restrict__ S) {
  int b = blockIdx.x;
  float* A = S + ((size_t)b * 2 + 0) * 65536;
  float* Bm = S + ((size_t)b * 2 + 1) * 65536;
  __shared__ float fac[256], pivA[256], pivB[256];
  __shared__ float s_ip;
  int tid = threadIdx.x;
  int c = tid & 511;
  for (int p = 0; p < 256; ++p) {
    if (tid < 256) fac[tid] = A[(size_t)tid * 256 + p];
    else if (tid < 512) pivA[tid - 256] = A[(size_t)p * 256 + (tid - 256)];
    else if (tid < 768) pivB[tid - 512] = Bm[(size_t)p * 256 + (tid - 512)];
    if (tid == 1023) s_ip = 1.0f / A[(size_t)p * 256 + p];
    __syncthreads();
    float ip = s_ip;
    for (int r = (tid >> 9); r < 256; r += 2) {
      if (r == p) continue;
      float fr = fac[r] * ip;
      if (c < 256) {
        if (c > p) {
          size_t idx = (size_t)r * 256 + c;
          A[idx] = fmaf(-fr, pivA[c], A[idx]);
        }
      } else {
        int cb = c - 256;
        size_t idx = (size_t)r * 256 + cb;
        Bm[idx] = fmaf(-fr, pivB[cb], Bm[idx]);
      }
    }
    __syncthreads();
  }
  for (int idx = tid; idx < 65536; idx += 1024) {
    int r = idx >> 8;
    Bm[idx] = Bm[idx] / A[(size_t)r * 256 + r];
  }
}

// ---------------- row softmax stats (max, sumexp) over X rows ----------------
__global__ void rowstats(const float* __restrict__ S, float* __restrict__ stats) {
  int b = blockIdx.x;
  const float* X = S + ((size_t)b * 2 + 1) * 65536;
  int tid = threadIdx.x; int lane = tid & 63; int wv = tid >> 6;
  for (int rr = 0; rr < 64; ++rr) {
    int row = rr * 4 + wv;
    float x0 = X[row * 256 + lane];
    float x1 = X[row * 256 + lane + 64];
    float x2 = X[row * 256 + lane + 128];
    float x3 = X[row * 256 + lane + 192];
    float m = fmaxf(fmaxf(x0, x1), fmaxf(x2, x3));
    for (int o = 32; o > 0; o >>= 1) m = fmaxf(m, __shfl_xor(m, o, 64));
    float s = expf(x0 - m) + expf(x1 - m) + expf(x2 - m) + expf(x3 - m);
    for (int o = 32; o > 0; o >>= 1) s += __shfl_xor(s, o, 64);
    if (lane == 0) {
      stats[((size_t)b * 256 + row) * 2 + 0] = m;
      stats[((size_t)b * 256 + row) * 2 + 1] = s;
    }
  }
}

// ---------------- h[b,e] = sum_d qsum[b,d] * softmax(X[b,d,:])[e] ----------
__global__ void final_h(const float* __restrict__ S, const float* __restrict__ stats,
                        const float* __restrict__ uvec, float* __restrict__ out) {
  int b = blockIdx.x; int e = threadIdx.x;
  const float* X = S + ((size_t)b * 2 + 1) * 65536;
  const float* qs = uvec + ((size_t)2 * 32 + b) * DDIM;
  float acc = 0.f;
  for (int d = 0; d < 256; ++d) {
    float m = stats[((size_t)b * 256 + d) * 2 + 0];
    float s = stats[((size_t)b * 256 + d) * 2 + 1];
    acc += qs[d] * expf(X[d * 256 + e] - m) / s;
  }
  out[(size_t)b * 256 + e] = acc;
}

extern "C" void kernel_launch(void* const* d_in, const int* in_sizes, int n_in,
                              void* d_out, int out_size, void* d_ws, size_t ws_size,
                              hipStream_t stream) {
  const float* q  = (const float*)d_in[0];
  const float* k  = (const float*)d_in[1];
  const float* v  = (const float*)d_in[2];
  const float* Wq = (const float*)d_in[3];
  const float* bq = (const float*)d_in[4];
  const float* Wk = (const float*)d_in[5];
  const float* bk = (const float*)d_in[6];
  const float* Wv = (const float*)d_in[7];
  const float* bv = (const float*)d_in[8];
  float* out = (float*)d_out;

  float* ws   = (float*)d_ws;
  float* Gbuf = ws;                                    // [32][2][256][256]
  float* Tbuf = Gbuf + (size_t)32 * 2 * 65536;         // [32][2][256][256]
  float* Sbuf = Tbuf + (size_t)32 * 2 * 65536;         // [32][2][256][256]
  float* part = Sbuf + (size_t)32 * 2 * 65536;         // [16][3][32][256]
  float* svec = part + (size_t)16 * 3 * 32 * 256;      // [3][32][256]
  float* uvec = svec + (size_t)3 * 32 * 256;           // [3][32][256]
  float* stats = uvec + (size_t)3 * 32 * 256;          // [32][256][2]

  colsum_partial<<<dim3(16, 3, 32), 256, 0, stream>>>(q, k, v, part);
  colsum_reduce<<<dim3(3, 32), 256, 0, stream>>>(part, svec);
  gram64<<<dim3(16, 2, 32), 256, 0, stream>>>(k, v, Gbuf);
  smallvec<<<32, 256, 0, stream>>>(Wq, bq, Wk, Wv, svec, uvec);
  gemm_pass1<<<dim3(16, 2, 32), 256, 0, stream>>>(Wk, Gbuf, Tbuf);
  gemm_pass2<<<dim3(16, 2, 32), 256, 0, stream>>>(Tbuf, Wk, Wv, Sbuf);
  rank1<<<dim3(256, 2, 32), 256, 0, stream>>>(Sbuf, uvec, bk, bv);
  gj_solve<<<32, 1024, 0, stream>>>(Sbuf);
  rowstats<<<32, 256, 0, stream>>>(Sbuf, stats);
  final_h<<<32, 256, 0, stream>>>(Sbuf, stats, uvec, out);
}

// Round 2
// 4698.523 us; speedup vs baseline: 1.5655x; 1.5655x over previous
//
#include <hip/hip_runtime.h>
#include <math.h>

#define FDIM 4096
#define DDIM 256
#define ALPHA_R 0.001f

// ---------------- column sums: s = sum_f x[b,f,:] ----------------
__global__ void colsum_partial(const float* __restrict__ q,
                               const float* __restrict__ k,
                               const float* __restrict__ v,
                               float* __restrict__ part) {
  int chunk = blockIdx.x;   // 16
  int which = blockIdx.y;   // 3: 0=q 1=k 2=v
  int b     = blockIdx.z;   // 32
  const float* x = (which == 0) ? q : (which == 1 ? k : v);
  int d = threadIdx.x;
  int f0 = chunk * (FDIM / 16);
  const float* p = x + ((size_t)b * FDIM + f0) * DDIM + d;
  float s = 0.f;
  for (int i = 0; i < FDIM / 16; ++i) s += p[(size_t)i * DDIM];
  part[(((size_t)chunk * 3 + which) * 32 + b) * DDIM + d] = s;
}

__global__ void colsum_reduce(const float* __restrict__ part,
                              float* __restrict__ svec) {
  int which = blockIdx.x; int b = blockIdx.y; int d = threadIdx.x;
  float s = 0.f;
  for (int c = 0; c < 16; ++c)
    s += part[(((size_t)c * 3 + which) * 32 + b) * DDIM + d];
  svec[((size_t)which * 32 + b) * DDIM + d] = s;
}

// ---------------- batched Gram: G[b][0]=k^T k, G[b][1]=k^T v ----------------
__global__ __launch_bounds__(256) void gram64(const float* __restrict__ kk,
                                              const float* __restrict__ vv,
                                              float* __restrict__ G) {
  int tile = blockIdx.x;      // 16 = 4x4
  int which = blockIdx.y;     // 2
  int b = blockIdx.z;         // 32
  int tm = tile >> 2, tn = tile & 3;
  const float* X = kk + (size_t)b * FDIM * DDIM;
  const float* Y = (which ? vv : kk) + (size_t)b * FDIM * DDIM;
  int mBase = tm * 64, nBase = tn * 64;
  __shared__ __align__(16) float Xs[16][64];
  __shared__ __align__(16) float Ys[16][64];
  int tid = threadIdx.x;
  int row = tid >> 4, col4 = tid & 15;
  int ty = tid >> 4, tx = tid & 15;
  float mac[4][4], cac[4][4];
#pragma unroll
  for (int i = 0; i < 4; i++)
#pragma unroll
    for (int j = 0; j < 4; j++) { mac[i][j] = 0.f; cac[i][j] = 0.f; }

  for (int it = 0; it < FDIM / 16; ++it) {
    int f0 = it * 16;
    const float4 a4 = *(const float4*)(X + (size_t)(f0 + row) * DDIM + mBase + col4 * 4);
    const float4 b4 = *(const float4*)(Y + (size_t)(f0 + row) * DDIM + nBase + col4 * 4);
    __syncthreads();
    *(float4*)&Xs[row][col4 * 4] = a4;
    *(float4*)&Ys[row][col4 * 4] = b4;
    __syncthreads();
#pragma unroll
    for (int kstep = 0; kstep < 16; ++kstep) {
      float4 a = *(const float4*)&Xs[kstep][ty * 4];
      float4 bb = *(const float4*)&Ys[kstep][tx * 4];
      float av[4] = {a.x, a.y, a.z, a.w};
      float bvv[4] = {bb.x, bb.y, bb.z, bb.w};
#pragma unroll
      for (int i = 0; i < 4; i++)
#pragma unroll
        for (int j = 0; j < 4; j++)
          cac[i][j] = fmaf(av[i], bvv[j], cac[i][j]);
    }
    if ((it & 7) == 7) {
#pragma unroll
      for (int i = 0; i < 4; i++)
#pragma unroll
        for (int j = 0; j < 4; j++) { mac[i][j] += cac[i][j]; cac[i][j] = 0.f; }
    }
  }
  float* C = G + (((size_t)b * 2 + which) * DDIM) * DDIM;
#pragma unroll
  for (int i = 0; i < 4; i++) {
    float4 o = make_float4(mac[i][0], mac[i][1], mac[i][2], mac[i][3]);
    *(float4*)(C + (size_t)(mBase + ty * 4 + i) * DDIM + nBase + tx * 4) = o;
  }
}

// ---------------- small vectors: uk=Wk sk, uv=Wv sv, qsum=Wq sq + F bq ------
__global__ void smallvec(const float* __restrict__ Wq, const float* __restrict__ bq,
                         const float* __restrict__ Wk, const float* __restrict__ Wv,
                         const float* __restrict__ svec, float* __restrict__ uvec) {
  int b = blockIdx.x; int d = threadIdx.x;
  __shared__ float sq[256], sk[256], sv[256];
  sq[d] = svec[((size_t)0 * 32 + b) * DDIM + d];
  sk[d] = svec[((size_t)1 * 32 + b) * DDIM + d];
  sv[d] = svec[((size_t)2 * 32 + b) * DDIM + d];
  __syncthreads();
  float uk = 0.f, uv = 0.f, uq = 0.f;
  for (int j = 0; j < 256; j += 4) {
    float4 wk4 = *(const float4*)(Wk + (size_t)d * DDIM + j);
    float4 wv4 = *(const float4*)(Wv + (size_t)d * DDIM + j);
    float4 wq4 = *(const float4*)(Wq + (size_t)d * DDIM + j);
    uk += wk4.x * sk[j] + wk4.y * sk[j + 1] + wk4.z * sk[j + 2] + wk4.w * sk[j + 3];
    uv += wv4.x * sv[j] + wv4.y * sv[j + 1] + wv4.z * sv[j + 2] + wv4.w * sv[j + 3];
    uq += wq4.x * sq[j] + wq4.y * sq[j + 1] + wq4.z * sq[j + 2] + wq4.w * sq[j + 3];
  }
  uvec[((size_t)0 * 32 + b) * DDIM + d] = uk;
  uvec[((size_t)1 * 32 + b) * DDIM + d] = uv;
  uvec[((size_t)2 * 32 + b) * DDIM + d] = uq + 4096.f * bq[d];
}

// ---------------- T[b][w] = Wk @ G[b][w]  (nn GEMM) ----------------
__global__ __launch_bounds__(256) void gemm_pass1(const float* __restrict__ Wk,
                                                  const float* __restrict__ G,
                                                  float* __restrict__ T) {
  int tile = blockIdx.x, w = blockIdx.y, b = blockIdx.z;
  int tm = tile >> 2, tn = tile & 3;
  const float* A = Wk;
  const float* B = G + ((size_t)b * 2 + w) * 65536;
  float* C = T + ((size_t)b * 2 + w) * 65536;
  __shared__ __align__(16) float As[16][64];
  __shared__ __align__(16) float Bs[16][64];
  int tid = threadIdx.x;
  int ty = tid >> 4, tx = tid & 15;
  int am = tid & 63, ak4 = tid >> 6;
  int brow = tid >> 4, bcol4 = tid & 15;
  int mBase = tm * 64, nBase = tn * 64;
  float acc[4][4];
#pragma unroll
  for (int i = 0; i < 4; i++)
#pragma unroll
    for (int j = 0; j < 4; j++) acc[i][j] = 0.f;
  for (int k0 = 0; k0 < 256; k0 += 16) {
    float4 a = *(const float4*)(A + (size_t)(mBase + am) * DDIM + k0 + ak4 * 4);
    float4 bb = *(const float4*)(B + (size_t)(k0 + brow) * DDIM + nBase + bcol4 * 4);
    __syncthreads();
    As[ak4 * 4 + 0][am] = a.x; As[ak4 * 4 + 1][am] = a.y;
    As[ak4 * 4 + 2][am] = a.z; As[ak4 * 4 + 3][am] = a.w;
    *(float4*)&Bs[brow][bcol4 * 4] = bb;
    __syncthreads();
#pragma unroll
    for (int kstep = 0; kstep < 16; ++kstep) {
      float4 a4 = *(const float4*)&As[kstep][ty * 4];
      float4 b4 = *(const float4*)&Bs[kstep][tx * 4];
      float av[4] = {a4.x, a4.y, a4.z, a4.w};
      float bvv[4] = {b4.x, b4.y, b4.z, b4.w};
#pragma unroll
      for (int i = 0; i < 4; i++)
#pragma unroll
        for (int j = 0; j < 4; j++)
          acc[i][j] = fmaf(av[i], bvv[j], acc[i][j]);
    }
  }
#pragma unroll
  for (int i = 0; i < 4; i++) {
    float4 o = make_float4(acc[i][0], acc[i][1], acc[i][2], acc[i][3]);
    *(float4*)(C + (size_t)(mBase + ty * 4 + i) * DDIM + nBase + tx * 4) = o;
  }
}

// ---------------- S[b][w] = T[b][w] @ W^T  (nt GEMM) ----------------
__global__ __launch_bounds__(256) void gemm_pass2(const float* __restrict__ T,
                                                  const float* __restrict__ Wk,
                                                  const float* __restrict__ Wv,
                                                  float* __restrict__ S) {
  int tile = blockIdx.x, w = blockIdx.y, b = blockIdx.z;
  int tm = tile >> 2, tn = tile & 3;
  const float* A = T + ((size_t)b * 2 + w) * 65536;
  const float* W = w ? Wv : Wk;
  float* C = S + ((size_t)b * 2 + w) * 65536;
  __shared__ __align__(16) float As[16][64];
  __shared__ __align__(16) float Bs[16][64];
  int tid = threadIdx.x;
  int ty = tid >> 4, tx = tid & 15;
  int am = tid & 63, ak4 = tid >> 6;
  int mBase = tm * 64, nBase = tn * 64;
  float acc[4][4];
#pragma unroll
  for (int i = 0; i < 4; i++)
#pragma unroll
    for (int j = 0; j < 4; j++) acc[i][j] = 0.f;
  for (int k0 = 0; k0 < 256; k0 += 16) {
    float4 a = *(const float4*)(A + (size_t)(mBase + am) * DDIM + k0 + ak4 * 4);
    float4 bb = *(const float4*)(W + (size_t)(nBase + am) * DDIM + k0 + ak4 * 4);
    __syncthreads();
    As[ak4 * 4 + 0][am] = a.x; As[ak4 * 4 + 1][am] = a.y;
    As[ak4 * 4 + 2][am] = a.z; As[ak4 * 4 + 3][am] = a.w;
    Bs[ak4 * 4 + 0][am] = bb.x; Bs[ak4 * 4 + 1][am] = bb.y;
    Bs[ak4 * 4 + 2][am] = bb.z; Bs[ak4 * 4 + 3][am] = bb.w;
    __syncthreads();
#pragma unroll
    for (int kstep = 0; kstep < 16; ++kstep) {
      float4 a4 = *(const float4*)&As[kstep][ty * 4];
      float4 b4 = *(const float4*)&Bs[kstep][tx * 4];
      float av[4] = {a4.x, a4.y, a4.z, a4.w};
      float bvv[4] = {b4.x, b4.y, b4.z, b4.w};
#pragma unroll
      for (int i = 0; i < 4; i++)
#pragma unroll
        for (int j = 0; j < 4; j++)
          acc[i][j] = fmaf(av[i], bvv[j], acc[i][j]);
    }
  }
#pragma unroll
  for (int i = 0; i < 4; i++) {
    float4 o = make_float4(acc[i][0], acc[i][1], acc[i][2], acc[i][3]);
    *(float4*)(C + (size_t)(mBase + ty * 4 + i) * DDIM + nBase + tx * 4) = o;
  }
}

// ---------------- rank-1 bias terms + alpha*I ----------------
__global__ void rank1(float* __restrict__ S, const float* __restrict__ uvec,
                      const float* __restrict__ bk, const float* __restrict__ bv) {
  int d = blockIdx.x, w = blockIdx.y, b = blockIdx.z;
  int e = threadIdx.x;
  float* row = S + (((size_t)b * 2 + w) * DDIM + d) * DDIM;
  float ukd = uvec[((size_t)0 * 32 + b) * DDIM + d];
  float bkd = bk[d];
  if (w == 0) {
    float uke = uvec[((size_t)0 * 32 + b) * DDIM + e];
    float add = ukd * bk[e] + bkd * uke + 4096.f * bkd * bk[e] + ((d == e) ? ALPHA_R : 0.f);
    row[e] += add;
  } else {
    float uve = uvec[((size_t)1 * 32 + b) * DDIM + e];
    float add = ukd * bv[e] + bkd * uve + 4096.f * bkd * bv[e];
    row[e] += add;
  }
}

// ---------------- register-resident Gauss-Jordan inversion of S[b][0] -------
// 1024 threads: thread (r=tid>>2, cg=tid&3) owns A[r, cg*64 .. cg*64+63] in
// 64 VGPRs (all indices compile-time). Per pivot: stage pivot row (stride-68
// padded LDS, bank-clean for the 4 column groups) + pivot column, 2 barriers.
__global__ __launch_bounds__(1024) void gj_invert(float* __restrict__ S) {
  int b = blockIdx.x;
  float* A = S + (size_t)b * 2 * 65536;
  int tid = threadIdx.x;
  int r = tid >> 2;
  int cg = tid & 3;
  __shared__ float prow[4 * 68];
  __shared__ float fac[256];
  float x[64];
  {
    const float* Ar = A + (size_t)r * 256 + cg * 64;
#pragma unroll
    for (int j4 = 0; j4 < 16; ++j4) {
      float4 t = *(const float4*)(Ar + j4 * 4);
      x[j4 * 4 + 0] = t.x; x[j4 * 4 + 1] = t.y;
      x[j4 * 4 + 2] = t.z; x[j4 * 4 + 3] = t.w;
    }
  }
  int cbase = cg * 68;
  for (int pg = 0; pg < 4; ++pg) {
#pragma unroll
    for (int pj = 0; pj < 64; ++pj) {
      int p = pg * 64 + pj;
      if (r == p) {
#pragma unroll
        for (int j4 = 0; j4 < 16; ++j4) {
          float4 t = make_float4(x[j4 * 4], x[j4 * 4 + 1], x[j4 * 4 + 2], x[j4 * 4 + 3]);
          *(float4*)&prow[cbase + j4 * 4] = t;
        }
      }
      if (cg == pg) fac[r] = x[pj];
      __syncthreads();
      float piv = fac[p];
      float ip = 1.0f / piv;
      float f = fac[r];
      float g = f * ip;
      bool diag = (r == p);
#pragma unroll
      for (int j4 = 0; j4 < 16; ++j4) {
        float4 pv = *(const float4*)&prow[cbase + j4 * 4];
        if (diag) {
          x[j4 * 4 + 0] = pv.x * ip; x[j4 * 4 + 1] = pv.y * ip;
          x[j4 * 4 + 2] = pv.z * ip; x[j4 * 4 + 3] = pv.w * ip;
        } else {
          x[j4 * 4 + 0] = fmaf(-g, pv.x, x[j4 * 4 + 0]);
          x[j4 * 4 + 1] = fmaf(-g, pv.y, x[j4 * 4 + 1]);
          x[j4 * 4 + 2] = fmaf(-g, pv.z, x[j4 * 4 + 2]);
          x[j4 * 4 + 3] = fmaf(-g, pv.w, x[j4 * 4 + 3]);
        }
      }
      if (cg == pg) x[pj] = diag ? ip : -g;
      __syncthreads();
    }
  }
  {
    float* Ar = A + (size_t)r * 256 + cg * 64;
#pragma unroll
    for (int j4 = 0; j4 < 16; ++j4) {
      float4 t = make_float4(x[j4 * 4], x[j4 * 4 + 1], x[j4 * 4 + 2], x[j4 * 4 + 3]);
      *(float4*)(Ar + j4 * 4) = t;
    }
  }
}

// ---------------- X[b] = Ainv[b] @ B[b]  (nn GEMM, batched) ----------------
__global__ __launch_bounds__(256) void gemm_xb(const float* __restrict__ S,
                                               float* __restrict__ T) {
  int tile = blockIdx.x, b = blockIdx.y;
  int tm = tile >> 2, tn = tile & 3;
  const float* A = S + (size_t)b * 2 * 65536;          // Ainv
  const float* B = S + ((size_t)b * 2 + 1) * 65536;    // rhs (k^T v projected)
  float* C = T + (size_t)b * 2 * 65536;                // X
  __shared__ __align__(16) float As[16][64];
  __shared__ __align__(16) float Bs[16][64];
  int tid = threadIdx.x;
  int ty = tid >> 4, tx = tid & 15;
  int am = tid & 63, ak4 = tid >> 6;
  int brow = tid >> 4, bcol4 = tid & 15;
  int mBase = tm * 64, nBase = tn * 64;
  float acc[4][4];
#pragma unroll
  for (int i = 0; i < 4; i++)
#pragma unroll
    for (int j = 0; j < 4; j++) acc[i][j] = 0.f;
  for (int k0 = 0; k0 < 256; k0 += 16) {
    float4 a = *(const float4*)(A + (size_t)(mBase + am) * DDIM + k0 + ak4 * 4);
    float4 bb = *(const float4*)(B + (size_t)(k0 + brow) * DDIM + nBase + bcol4 * 4);
    __syncthreads();
    As[ak4 * 4 + 0][am] = a.x; As[ak4 * 4 + 1][am] = a.y;
    As[ak4 * 4 + 2][am] = a.z; As[ak4 * 4 + 3][am] = a.w;
    *(float4*)&Bs[brow][bcol4 * 4] = bb;
    __syncthreads();
#pragma unroll
    for (int kstep = 0; kstep < 16; ++kstep) {
      float4 a4 = *(const float4*)&As[kstep][ty * 4];
      float4 b4 = *(const float4*)&Bs[kstep][tx * 4];
      float av[4] = {a4.x, a4.y, a4.z, a4.w};
      float bvv[4] = {b4.x, b4.y, b4.z, b4.w};
#pragma unroll
      for (int i = 0; i < 4; i++)
#pragma unroll
        for (int j = 0; j < 4; j++)
          acc[i][j] = fmaf(av[i], bvv[j], acc[i][j]);
    }
  }
#pragma unroll
  for (int i = 0; i < 4; i++) {
    float4 o = make_float4(acc[i][0], acc[i][1], acc[i][2], acc[i][3]);
    *(float4*)(C + (size_t)(mBase + ty * 4 + i) * DDIM + nBase + tx * 4) = o;
  }
}

// ---------------- row softmax stats (max, sumexp) over X rows ----------------
__global__ void rowstats(const float* __restrict__ T, float* __restrict__ stats) {
  int b = blockIdx.x;
  const float* X = T + (size_t)b * 2 * 65536;
  int tid = threadIdx.x; int lane = tid & 63; int wv = tid >> 6;
  for (int rr = 0; rr < 64; ++rr) {
    int row = rr * 4 + wv;
    float x0 = X[row * 256 + lane];
    float x1 = X[row * 256 + lane + 64];
    float x2 = X[row * 256 + lane + 128];
    float x3 = X[row * 256 + lane + 192];
    float m = fmaxf(fmaxf(x0, x1), fmaxf(x2, x3));
    for (int o = 32; o > 0; o >>= 1) m = fmaxf(m, __shfl_xor(m, o, 64));
    float s = expf(x0 - m) + expf(x1 - m) + expf(x2 - m) + expf(x3 - m);
    for (int o = 32; o > 0; o >>= 1) s += __shfl_xor(s, o, 64);
    if (lane == 0) {
      stats[((size_t)b * 256 + row) * 2 + 0] = m;
      stats[((size_t)b * 256 + row) * 2 + 1] = s;
    }
  }
}

// ---------------- h[b,e] = sum_d qsum[b,d] * softmax(X[b,d,:])[e] ----------
__global__ void final_h(const float* __restrict__ T, const float* __restrict__ stats,
                        const float* __restrict__ uvec, float* __restrict__ out) {
  int b = blockIdx.x; int e = threadIdx.x;
  const float* X = T + (size_t)b * 2 * 65536;
  const float* qs = uvec + ((size_t)2 * 32 + b) * DDIM;
  float acc = 0.f;
  for (int d = 0; d < 256; ++d) {
    float m = stats[((size_t)b * 256 + d) * 2 + 0];
    float s = stats[((size_t)b * 256 + d) * 2 + 1];
    acc += qs[d] * expf(X[d * 256 + e] - m) / s;
  }
  out[(size_t)b * 256 + e] = acc;
}

extern "C" void kernel_launch(void* const* d_in, const int* in_sizes, int n_in,
                              void* d_out, int out_size, void* d_ws, size_t ws_size,
                              hipStream_t stream) {
  const float* q  = (const float*)d_in[0];
  const float* k  = (const float*)d_in[1];
  const float* v  = (const float*)d_in[2];
  const float* Wq = (const float*)d_in[3];
  const float* bq = (const float*)d_in[4];
  const float* Wk = (const float*)d_in[5];
  const float* bk = (const float*)d_in[6];
  const float* Wv = (const float*)d_in[7];
  const float* bv = (const float*)d_in[8];
  float* out = (float*)d_out;

  float* ws   = (float*)d_ws;
  float* Gbuf = ws;                                    // [32][2][256][256]
  float* Tbuf = Gbuf + (size_t)32 * 2 * 65536;         // [32][2][256][256] (X lives in [b][0])
  float* Sbuf = Tbuf + (size_t)32 * 2 * 65536;         // [32][2][256][256] (A -> Ainv, B)
  float* part = Sbuf + (size_t)32 * 2 * 65536;         // [16][3][32][256]
  float* svec = part + (size_t)16 * 3 * 32 * 256;      // [3][32][256]
  float* uvec = svec + (size_t)3 * 32 * 256;           // [3][32][256]
  float* stats = uvec + (size_t)3 * 32 * 256;          // [32][256][2]

  colsum_partial<<<dim3(16, 3, 32), 256, 0, stream>>>(q, k, v, part);
  colsum_reduce<<<dim3(3, 32), 256, 0, stream>>>(part, svec);
  gram64<<<dim3(16, 2, 32), 256, 0, stream>>>(k, v, Gbuf);
  smallvec<<<32, 256, 0, stream>>>(Wq, bq, Wk, Wv, svec, uvec);
  gemm_pass1<<<dim3(16, 2, 32), 256, 0, stream>>>(Wk, Gbuf, Tbuf);
  gemm_pass2<<<dim3(16, 2, 32), 256, 0, stream>>>(Tbuf, Wk, Wv, Sbuf);
  rank1<<<dim3(256, 2, 32), 256, 0, stream>>>(Sbuf, uvec, bk, bv);
  gj_invert<<<32, 1024, 0, stream>>>(Sbuf);
  gemm_xb<<<dim3(16, 32), 256, 0, stream>>>(Sbuf, Tbuf);
  rowstats<<<32, 256, 0, stream>>>(Tbuf, stats);
  final_h<<<32, 256, 0, stream>>>(Tbuf, stats, uvec, out);
}

// Round 3
// 1015.140 us; speedup vs baseline: 7.2459x; 4.6284x over previous
//
#include <hip/hip_runtime.h>
#include <math.h>

#define FDIM 4096
#define DDIM 256
#define ALPHA_R 0.001f

// ---------------- column sums: s = sum_f x[b,f,:] ----------------
__global__ void colsum_partial(const float* __restrict__ q,
                               const float* __restrict__ k,
                               const float* __restrict__ v,
                               float* __restrict__ part) {
  int chunk = blockIdx.x;   // 16
  int which = blockIdx.y;   // 3: 0=q 1=k 2=v
  int b     = blockIdx.z;   // 32
  const float* x = (which == 0) ? q : (which == 1 ? k : v);
  int d = threadIdx.x;
  int f0 = chunk * (FDIM / 16);
  const float* p = x + ((size_t)b * FDIM + f0) * DDIM + d;
  float s = 0.f;
  for (int i = 0; i < FDIM / 16; ++i) s += p[(size_t)i * DDIM];
  part[(((size_t)chunk * 3 + which) * 32 + b) * DDIM + d] = s;
}

__global__ void colsum_reduce(const float* __restrict__ part,
                              float* __restrict__ svec) {
  int which = blockIdx.x; int b = blockIdx.y; int d = threadIdx.x;
  float s = 0.f;
  for (int c = 0; c < 16; ++c)
    s += part[(((size_t)c * 3 + which) * 32 + b) * DDIM + d];
  svec[((size_t)which * 32 + b) * DDIM + d] = s;
}

// ---------------- batched Gram: G[b][0]=k^T k, G[b][1]=k^T v ----------------
__global__ __launch_bounds__(256) void gram64(const float* __restrict__ kk,
                                              const float* __restrict__ vv,
                                              float* __restrict__ G) {
  int tile = blockIdx.x;      // 16 = 4x4
  int which = blockIdx.y;     // 2
  int b = blockIdx.z;         // 32
  int tm = tile >> 2, tn = tile & 3;
  const float* X = kk + (size_t)b * FDIM * DDIM;
  const float* Y = (which ? vv : kk) + (size_t)b * FDIM * DDIM;
  int mBase = tm * 64, nBase = tn * 64;
  __shared__ __align__(16) float Xs[16][64];
  __shared__ __align__(16) float Ys[16][64];
  int tid = threadIdx.x;
  int row = tid >> 4, col4 = tid & 15;
  int ty = tid >> 4, tx = tid & 15;
  float mac[4][4], cac[4][4];
#pragma unroll
  for (int i = 0; i < 4; i++)
#pragma unroll
    for (int j = 0; j < 4; j++) { mac[i][j] = 0.f; cac[i][j] = 0.f; }

  for (int it = 0; it < FDIM / 16; ++it) {
    int f0 = it * 16;
    const float4 a4 = *(const float4*)(X + (size_t)(f0 + row) * DDIM + mBase + col4 * 4);
    const float4 b4 = *(const float4*)(Y + (size_t)(f0 + row) * DDIM + nBase + col4 * 4);
    __syncthreads();
    *(float4*)&Xs[row][col4 * 4] = a4;
    *(float4*)&Ys[row][col4 * 4] = b4;
    __syncthreads();
#pragma unroll
    for (int kstep = 0; kstep < 16; ++kstep) {
      float4 a = *(const float4*)&Xs[kstep][ty * 4];
      float4 bb = *(const float4*)&Ys[kstep][tx * 4];
      float av[4] = {a.x, a.y, a.z, a.w};
      float bvv[4] = {bb.x, bb.y, bb.z, bb.w};
#pragma unroll
      for (int i = 0; i < 4; i++)
#pragma unroll
        for (int j = 0; j < 4; j++)
          cac[i][j] = fmaf(av[i], bvv[j], cac[i][j]);
    }
    if ((it & 7) == 7) {
#pragma unroll
      for (int i = 0; i < 4; i++)
#pragma unroll
        for (int j = 0; j < 4; j++) { mac[i][j] += cac[i][j]; cac[i][j] = 0.f; }
    }
  }
  float* C = G + (((size_t)b * 2 + which) * DDIM) * DDIM;
#pragma unroll
  for (int i = 0; i < 4; i++) {
    float4 o = make_float4(mac[i][0], mac[i][1], mac[i][2], mac[i][3]);
    *(float4*)(C + (size_t)(mBase + ty * 4 + i) * DDIM + nBase + tx * 4) = o;
  }
}

// ---------------- small vectors: uk=Wk sk, uv=Wv sv, qsum=Wq sq + F bq ------
__global__ void smallvec(const float* __restrict__ Wq, const float* __restrict__ bq,
                         const float* __restrict__ Wk, const float* __restrict__ Wv,
                         const float* __restrict__ svec, float* __restrict__ uvec) {
  int b = blockIdx.x; int d = threadIdx.x;
  __shared__ float sq[256], sk[256], sv[256];
  sq[d] = svec[((size_t)0 * 32 + b) * DDIM + d];
  sk[d] = svec[((size_t)1 * 32 + b) * DDIM + d];
  sv[d] = svec[((size_t)2 * 32 + b) * DDIM + d];
  __syncthreads();
  float uk = 0.f, uv = 0.f, uq = 0.f;
  for (int j = 0; j < 256; j += 4) {
    float4 wk4 = *(const float4*)(Wk + (size_t)d * DDIM + j);
    float4 wv4 = *(const float4*)(Wv + (size_t)d * DDIM + j);
    float4 wq4 = *(const float4*)(Wq + (size_t)d * DDIM + j);
    uk += wk4.x * sk[j] + wk4.y * sk[j + 1] + wk4.z * sk[j + 2] + wk4.w * sk[j + 3];
    uv += wv4.x * sv[j] + wv4.y * sv[j + 1] + wv4.z * sv[j + 2] + wv4.w * sv[j + 3];
    uq += wq4.x * sq[j] + wq4.y * sq[j + 1] + wq4.z * sq[j + 2] + wq4.w * sq[j + 3];
  }
  uvec[((size_t)0 * 32 + b) * DDIM + d] = uk;
  uvec[((size_t)1 * 32 + b) * DDIM + d] = uv;
  uvec[((size_t)2 * 32 + b) * DDIM + d] = uq + 4096.f * bq[d];
}

// ---------------- T[b][w] = Wk @ G[b][w]  (nn GEMM) ----------------
__global__ __launch_bounds__(256) void gemm_pass1(const float* __restrict__ Wk,
                                                  const float* __restrict__ G,
                                                  float* __restrict__ T) {
  int tile = blockIdx.x, w = blockIdx.y, b = blockIdx.z;
  int tm = tile >> 2, tn = tile & 3;
  const float* A = Wk;
  const float* B = G + ((size_t)b * 2 + w) * 65536;
  float* C = T + ((size_t)b * 2 + w) * 65536;
  __shared__ __align__(16) float As[16][64];
  __shared__ __align__(16) float Bs[16][64];
  int tid = threadIdx.x;
  int ty = tid >> 4, tx = tid & 15;
  int am = tid & 63, ak4 = tid >> 6;
  int brow = tid >> 4, bcol4 = tid & 15;
  int mBase = tm * 64, nBase = tn * 64;
  float acc[4][4];
#pragma unroll
  for (int i = 0; i < 4; i++)
#pragma unroll
    for (int j = 0; j < 4; j++) acc[i][j] = 0.f;
  for (int k0 = 0; k0 < 256; k0 += 16) {
    float4 a = *(const float4*)(A + (size_t)(mBase + am) * DDIM + k0 + ak4 * 4);
    float4 bb = *(const float4*)(B + (size_t)(k0 + brow) * DDIM + nBase + bcol4 * 4);
    __syncthreads();
    As[ak4 * 4 + 0][am] = a.x; As[ak4 * 4 + 1][am] = a.y;
    As[ak4 * 4 + 2][am] = a.z; As[ak4 * 4 + 3][am] = a.w;
    *(float4*)&Bs[brow][bcol4 * 4] = bb;
    __syncthreads();
#pragma unroll
    for (int kstep = 0; kstep < 16; ++kstep) {
      float4 a4 = *(const float4*)&As[kstep][ty * 4];
      float4 b4 = *(const float4*)&Bs[kstep][tx * 4];
      float av[4] = {a4.x, a4.y, a4.z, a4.w};
      float bvv[4] = {b4.x, b4.y, b4.z, b4.w};
#pragma unroll
      for (int i = 0; i < 4; i++)
#pragma unroll
        for (int j = 0; j < 4; j++)
          acc[i][j] = fmaf(av[i], bvv[j], acc[i][j]);
    }
  }
#pragma unroll
  for (int i = 0; i < 4; i++) {
    float4 o = make_float4(acc[i][0], acc[i][1], acc[i][2], acc[i][3]);
    *(float4*)(C + (size_t)(mBase + ty * 4 + i) * DDIM + nBase + tx * 4) = o;
  }
}

// ---------------- S[b][w] = T[b][w] @ W^T  (nt GEMM) ----------------
__global__ __launch_bounds__(256) void gemm_pass2(const float* __restrict__ T,
                                                  const float* __restrict__ Wk,
                                                  const float* __restrict__ Wv,
                                                  float* __restrict__ S) {
  int tile = blockIdx.x, w = blockIdx.y, b = blockIdx.z;
  int tm = tile >> 2, tn = tile & 3;
  const float* A = T + ((size_t)b * 2 + w) * 65536;
  const float* W = w ? Wv : Wk;
  float* C = S + ((size_t)b * 2 + w) * 65536;
  __shared__ __align__(16) float As[16][64];
  __shared__ __align__(16) float Bs[16][64];
  int tid = threadIdx.x;
  int ty = tid >> 4, tx = tid & 15;
  int am = tid & 63, ak4 = tid >> 6;
  int mBase = tm * 64, nBase = tn * 64;
  float acc[4][4];
#pragma unroll
  for (int i = 0; i < 4; i++)
#pragma unroll
    for (int j = 0; j < 4; j++) acc[i][j] = 0.f;
  for (int k0 = 0; k0 < 256; k0 += 16) {
    float4 a = *(const float4*)(A + (size_t)(mBase + am) * DDIM + k0 + ak4 * 4);
    float4 bb = *(const float4*)(W + (size_t)(nBase + am) * DDIM + k0 + ak4 * 4);
    __syncthreads();
    As[ak4 * 4 + 0][am] = a.x; As[ak4 * 4 + 1][am] = a.y;
    As[ak4 * 4 + 2][am] = a.z; As[ak4 * 4 + 3][am] = a.w;
    Bs[ak4 * 4 + 0][am] = bb.x; Bs[ak4 * 4 + 1][am] = bb.y;
    Bs[ak4 * 4 + 2][am] = bb.z; Bs[ak4 * 4 + 3][am] = bb.w;
    __syncthreads();
#pragma unroll
    for (int kstep = 0; kstep < 16; ++kstep) {
      float4 a4 = *(const float4*)&As[kstep][ty * 4];
      float4 b4 = *(const float4*)&Bs[kstep][tx * 4];
      float av[4] = {a4.x, a4.y, a4.z, a4.w};
      float bvv[4] = {b4.x, b4.y, b4.z, b4.w};
#pragma unroll
      for (int i = 0; i < 4; i++)
#pragma unroll
        for (int j = 0; j < 4; j++)
          acc[i][j] = fmaf(av[i], bvv[j], acc[i][j]);
    }
  }
#pragma unroll
  for (int i = 0; i < 4; i++) {
    float4 o = make_float4(acc[i][0], acc[i][1], acc[i][2], acc[i][3]);
    *(float4*)(C + (size_t)(mBase + ty * 4 + i) * DDIM + nBase + tx * 4) = o;
  }
}

// ---------------- rank-1 bias terms + alpha*I ----------------
__global__ void rank1(float* __restrict__ S, const float* __restrict__ uvec,
                      const float* __restrict__ bk, const float* __restrict__ bv) {
  int d = blockIdx.x, w = blockIdx.y, b = blockIdx.z;
  int e = threadIdx.x;
  float* row = S + (((size_t)b * 2 + w) * DDIM + d) * DDIM;
  float ukd = uvec[((size_t)0 * 32 + b) * DDIM + d];
  float bkd = bk[d];
  if (w == 0) {
    float uke = uvec[((size_t)0 * 32 + b) * DDIM + e];
    float add = ukd * bk[e] + bkd * uke + 4096.f * bkd * bk[e] + ((d == e) ? ALPHA_R : 0.f);
    row[e] += add;
  } else {
    float uve = uvec[((size_t)1 * 32 + b) * DDIM + e];
    float add = ukd * bv[e] + bkd * uve + 4096.f * bkd * bv[e];
    row[e] += add;
  }
}

// ---------------- blocked Gauss-Jordan solve: Sb[b][1] <- Sb[b][0]^-1 Sb[b][1]
// One block (1024 thr) per batch. Panels of 64 columns:
//   factor: panel in REGISTERS, 16 floats/thread, thread (r=tid>>2, q=tid&3)
//           owns P[r][q*16..q*16+15]; all register indices compile-time.
//   update: E differs from I only in panel cols (matrix M, 256x64).
//           Anew[r,c] = [r notin panel]*A[r,c] + sum_j M[r,j]*A[p_j,c]
//           applied to trailing A cols + all B cols as 8x8-register-tile GEMM
//           with M transposed in LDS (Mt) and pivot rows staged (Sst).
__global__ __launch_bounds__(1024, 4) void gj_solve(float* __restrict__ Sb) {
  int b = blockIdx.x;
  float* A  = Sb + (size_t)b * 2 * 65536;   // destroyed
  float* Bm = A + 65536;                    // becomes X
  int tid = threadIdx.x;
  int r = tid >> 2;          // 0..255 (factor-phase row)
  int q = tid & 3;           // col group of 16

  __shared__ __align__(16) float Mt[64][264];    // factored panel, transposed
  __shared__ __align__(16) float Sst[64][260];   // staged pivot rows chunk
  __shared__ __align__(16) float prow[64];
  __shared__ float fac[256];

  for (int pg = 0; pg < 4; ++pg) {
    // ---------------- factor panel pg (in registers) ----------------
    float x[16];
    {
      const float* Ar = A + (size_t)r * 256 + pg * 64 + q * 16;
#pragma unroll
      for (int m = 0; m < 4; ++m) {
        float4 t = *(const float4*)(Ar + m * 4);
        x[m * 4 + 0] = t.x; x[m * 4 + 1] = t.y;
        x[m * 4 + 2] = t.z; x[m * 4 + 3] = t.w;
      }
    }
#pragma unroll
    for (int jo = 0; jo < 4; ++jo) {
#pragma unroll
      for (int ji = 0; ji < 16; ++ji) {
        const int j = jo * 16 + ji;
        const int p = pg * 64 + j;          // global pivot row (runtime ok)
        if (r == p) {
          *(float4*)&prow[q * 16 + 0]  = make_float4(x[0], x[1], x[2], x[3]);
          *(float4*)&prow[q * 16 + 4]  = make_float4(x[4], x[5], x[6], x[7]);
          *(float4*)&prow[q * 16 + 8]  = make_float4(x[8], x[9], x[10], x[11]);
          *(float4*)&prow[q * 16 + 12] = make_float4(x[12], x[13], x[14], x[15]);
        }
        if (q == jo) fac[r] = x[ji];        // ji compile-time
        __syncthreads();
        float piv = fac[p];
        float ip = 1.0f / piv;
        float f = fac[r];
        float g = f * ip;
        bool diag = (r == p);
#pragma unroll
        for (int m = 0; m < 16; ++m) {
          float pv = prow[q * 16 + m];
          x[m] = diag ? pv * ip : fmaf(-g, pv, x[m]);
        }
        if (q == jo) x[ji] = diag ? ip : (0.f - g);
        __syncthreads();
      }
    }
    // dump M transposed: Mt[j][r]
#pragma unroll
    for (int m = 0; m < 16; ++m) Mt[q * 16 + m][r] = x[m];
    __syncthreads();

    // ---------------- update chunks: trailing A cols, then B ----------------
    for (int chunk = 0; chunk < 2; ++chunk) {
      int W, c_off; float* Csrc;
      if (chunk == 0) {
        W = (3 - pg) * 64; c_off = (pg + 1) * 64; Csrc = A;
        if (W == 0) continue;
      } else {
        W = 256; c_off = 0; Csrc = Bm;
      }
      // stage pivot rows (64 x W)
      {
        int cpt = W >> 4;                    // 4,8,12,16
        int jr = tid >> 4, tc = tid & 15;
        const float* src = Csrc + (size_t)(pg * 64 + jr) * 256 + c_off + tc * cpt;
        for (int m = 0; m < cpt; m += 4) {
          float4 t = *(const float4*)(src + m);
          *(float4*)&Sst[jr][tc * cpt + m] = t;
        }
      }
      __syncthreads();
      // compute 8x8 tiles
      int colTiles = W >> 3;
      int rt = tid / colTiles;
      int ctile = tid - rt * colTiles;
      if (rt < 32) {
        int r0 = rt * 8, c0 = ctile * 8;
        float acc[8][8];
#pragma unroll
        for (int i = 0; i < 8; ++i)
#pragma unroll
          for (int j2 = 0; j2 < 8; ++j2) acc[i][j2] = 0.f;
        for (int j = 0; j < 64; ++j) {
          float4 m0 = *(const float4*)&Mt[j][r0];
          float4 m1 = *(const float4*)&Mt[j][r0 + 4];
          float4 s0 = *(const float4*)&Sst[j][c0];
          float4 s1 = *(const float4*)&Sst[j][c0 + 4];
          float mv[8] = {m0.x, m0.y, m0.z, m0.w, m1.x, m1.y, m1.z, m1.w};
          float sv[8] = {s0.x, s0.y, s0.z, s0.w, s1.x, s1.y, s1.z, s1.w};
#pragma unroll
          for (int i = 0; i < 8; ++i)
#pragma unroll
            for (int j2 = 0; j2 < 8; ++j2)
              acc[i][j2] = fmaf(mv[i], sv[j2], acc[i][j2]);
        }
#pragma unroll
        for (int ii = 0; ii < 8; ++ii) {
          int row = r0 + ii;
          bool inPanel = ((row >> 6) == pg);
          float* dst = Csrc + (size_t)row * 256 + c_off + c0;
          float4 o0 = make_float4(acc[ii][0], acc[ii][1], acc[ii][2], acc[ii][3]);
          float4 o1 = make_float4(acc[ii][4], acc[ii][5], acc[ii][6], acc[ii][7]);
          if (!inPanel) {
            float4 a0 = *(const float4*)(dst);
            float4 a1 = *(const float4*)(dst + 4);
            o0.x += a0.x; o0.y += a0.y; o0.z += a0.z; o0.w += a0.w;
            o1.x += a1.x; o1.y += a1.y; o1.z += a1.z; o1.w += a1.w;
          }
          *(float4*)(dst) = o0;
          *(float4*)(dst + 4) = o1;
        }
      }
      __syncthreads();
    }
  }
}

// ---------------- row softmax stats (max, sumexp) over X rows ----------------
__global__ void rowstats(const float* __restrict__ S, float* __restrict__ stats) {
  int b = blockIdx.x;
  const float* X = S + ((size_t)b * 2 + 1) * 65536;
  int tid = threadIdx.x; int lane = tid & 63; int wv = tid >> 6;
  for (int rr = 0; rr < 64; ++rr) {
    int row = rr * 4 + wv;
    float x0 = X[row * 256 + lane];
    float x1 = X[row * 256 + lane + 64];
    float x2 = X[row * 256 + lane + 128];
    float x3 = X[row * 256 + lane + 192];
    float m = fmaxf(fmaxf(x0, x1), fmaxf(x2, x3));
    for (int o = 32; o > 0; o >>= 1) m = fmaxf(m, __shfl_xor(m, o, 64));
    float s = expf(x0 - m) + expf(x1 - m) + expf(x2 - m) + expf(x3 - m);
    for (int o = 32; o > 0; o >>= 1) s += __shfl_xor(s, o, 64);
    if (lane == 0) {
      stats[((size_t)b * 256 + row) * 2 + 0] = m;
      stats[((size_t)b * 256 + row) * 2 + 1] = s;
    }
  }
}

// ---------------- h[b,e] = sum_d qsum[b,d] * softmax(X[b,d,:])[e] ----------
__global__ void final_h(const float* __restrict__ S, const float* __restrict__ stats,
                        const float* __restrict__ uvec, float* __restrict__ out) {
  int b = blockIdx.x; int e = threadIdx.x;
  const float* X = S + ((size_t)b * 2 + 1) * 65536;
  const float* qs = uvec + ((size_t)2 * 32 + b) * DDIM;
  float acc = 0.f;
  for (int d = 0; d < 256; ++d) {
    float m = stats[((size_t)b * 256 + d) * 2 + 0];
    float s = stats[((size_t)b * 256 + d) * 2 + 1];
    acc += qs[d] * expf(X[d * 256 + e] - m) / s;
  }
  out[(size_t)b * 256 + e] = acc;
}

extern "C" void kernel_launch(void* const* d_in, const int* in_sizes, int n_in,
                              void* d_out, int out_size, void* d_ws, size_t ws_size,
                              hipStream_t stream) {
  const float* q  = (const float*)d_in[0];
  const float* k  = (const float*)d_in[1];
  const float* v  = (const float*)d_in[2];
  const float* Wq = (const float*)d_in[3];
  const float* bq = (const float*)d_in[4];
  const float* Wk = (const float*)d_in[5];
  const float* bk = (const float*)d_in[6];
  const float* Wv = (const float*)d_in[7];
  const float* bv = (const float*)d_in[8];
  float* out = (float*)d_out;

  float* ws   = (float*)d_ws;
  float* Gbuf = ws;                                    // [32][2][256][256]
  float* Tbuf = Gbuf + (size_t)32 * 2 * 65536;         // [32][2][256][256]
  float* Sbuf = Tbuf + (size_t)32 * 2 * 65536;         // [32][2][256][256] (A, B->X)
  float* part = Sbuf + (size_t)32 * 2 * 65536;         // [16][3][32][256]
  float* svec = part + (size_t)16 * 3 * 32 * 256;      // [3][32][256]
  float* uvec = svec + (size_t)3 * 32 * 256;           // [3][32][256]
  float* stats = uvec + (size_t)3 * 32 * 256;          // [32][256][2]

  colsum_partial<<<dim3(16, 3, 32), 256, 0, stream>>>(q, k, v, part);
  colsum_reduce<<<dim3(3, 32), 256, 0, stream>>>(part, svec);
  gram64<<<dim3(16, 2, 32), 256, 0, stream>>>(k, v, Gbuf);
  smallvec<<<32, 256, 0, stream>>>(Wq, bq, Wk, Wv, svec, uvec);
  gemm_pass1<<<dim3(16, 2, 32), 256, 0, stream>>>(Wk, Gbuf, Tbuf);
  gemm_pass2<<<dim3(16, 2, 32), 256, 0, stream>>>(Tbuf, Wk, Wv, Sbuf);
  rank1<<<dim3(256, 2, 32), 256, 0, stream>>>(Sbuf, uvec, bk, bv);
  gj_solve<<<32, 1024, 0, stream>>>(Sbuf);
  rowstats<<<32, 256, 0, stream>>>(Sbuf, stats);
  final_h<<<32, 256, 0, stream>>>(Sbuf, stats, uvec, out);
}

// Round 4
// 732.986 us; speedup vs baseline: 10.0351x; 1.3849x over previous
//
#include <hip/hip_runtime.h>
#include <math.h>

#define FDIM 4096
#define DDIM 256
#define ALPHA_R 0.001f

typedef __attribute__((ext_vector_type(8))) short short8;
typedef __attribute__((ext_vector_type(4))) float f32x4;

__device__ __forceinline__ unsigned cvt_pk_bf16(float lo_e, float hi_e) {
  unsigned r;
  asm("v_cvt_pk_bf16_f32 %0, %1, %2" : "=v"(r) : "v"(lo_e), "v"(hi_e));
  return r;
}

// ---------------- column sums for q only ----------------
__global__ void colsum_partial_q(const float* __restrict__ q,
                                 float* __restrict__ part) {
  int chunk = blockIdx.x;   // 16
  int b     = blockIdx.y;   // 32
  int d = threadIdx.x;
  const float* p = q + ((size_t)b * FDIM + chunk * 256) * DDIM + d;
  float s = 0.f;
  for (int i = 0; i < 256; ++i) s += p[(size_t)i * DDIM];
  part[((size_t)chunk * 32 + b) * DDIM + d] = s;
}

__global__ void colsum_reduce_q(const float* __restrict__ part,
                                float* __restrict__ svec) {
  int b = blockIdx.x; int d = threadIdx.x;
  float s = 0.f;
  for (int c = 0; c < 16; ++c) s += part[((size_t)c * 32 + b) * DDIM + d];
  svec[(size_t)b * DDIM + d] = s;   // svec[0][b][d]
}

// ---------------- MFMA Gram: G[b][0]=k^T k, G[b][1]=k^T v (bf16 hi/lo x4) ---
// 512 blocks, 256 thr. Block = one 64x64 tile (tm,tn) of BOTH outputs for one
// batch. fp32 -> bf16 hi/lo staged K-major in LDS (pitch 40 shorts = 80B).
// Fuses k,v column sums (tn==0 / tm==0 blocks).
__global__ __launch_bounds__(256) void gram_mfma(const float* __restrict__ kg,
                                                 const float* __restrict__ vg,
                                                 float* __restrict__ G,
                                                 float* __restrict__ svec) {
  int flat = blockIdx.x;            // 512
  int xcd = flat & 7, s = flat >> 3;
  int b = xcd * 4 + (s >> 4);       // 4 batches per XCD, tiles co-resident
  int tile = s & 15;
  int tm = tile >> 2, tn = tile & 3;
  int mBase = tm * 64, nBase = tn * 64;
  const float* Kb = kg + (size_t)b * FDIM * DDIM;
  const float* Vb = vg + (size_t)b * FDIM * DDIM;

  __shared__ __align__(16) unsigned short Ah[64][40], Al[64][40];
  __shared__ __align__(16) unsigned short Bh[64][40], Bl[64][40];
  __shared__ __align__(16) unsigned short Ch[64][40], Cl[64][40];
  __shared__ float red[16][68];

  int tid = threadIdx.x;
  int dq = tid & 15;       // d-quad
  int fp = tid >> 4;       // f-pair 0..15
  int d0A = mBase + dq * 4, d0B = nBase + dq * 4;
  int dbase = dq * 4;

  bool doK = (tn == 0), doV = (tm == 0);
  float sK[4] = {0.f, 0.f, 0.f, 0.f}, sV[4] = {0.f, 0.f, 0.f, 0.f};

  float4 a0, a1, b0, b1, c0, c1;
  auto loadIter = [&](int it) {
    size_t ro = ((size_t)it * 32 + 2 * fp) * DDIM;
    a0 = *(const float4*)(Kb + ro + d0A);
    a1 = *(const float4*)(Kb + ro + DDIM + d0A);
    b0 = *(const float4*)(Kb + ro + d0B);
    b1 = *(const float4*)(Kb + ro + DDIM + d0B);
    c0 = *(const float4*)(Vb + ro + d0B);
    c1 = *(const float4*)(Vb + ro + DDIM + d0B);
  };
  auto stash = [&](const float4& r0, const float4& r1,
                   unsigned short (*Lh)[40], unsigned short (*Ll)[40]) {
    float e0[4] = {r0.x, r0.y, r0.z, r0.w};
    float e1[4] = {r1.x, r1.y, r1.z, r1.w};
#pragma unroll
    for (int i = 0; i < 4; ++i) {
      unsigned uh = cvt_pk_bf16(e0[i], e1[i]);
      float h0 = __uint_as_float(uh << 16);
      float h1 = __uint_as_float(uh & 0xFFFF0000u);
      unsigned ul = cvt_pk_bf16(e0[i] - h0, e1[i] - h1);
      *(unsigned*)&Lh[dbase + i][2 * fp] = uh;
      *(unsigned*)&Ll[dbase + i][2 * fp] = ul;
    }
  };

  int w = tid >> 6, lane = tid & 63;
  int wr = w >> 1, wc = w & 1;
  int lrow = lane & 15, kof = (lane >> 4) * 8;

  f32x4 acc0[2][2], acc1[2][2];
#pragma unroll
  for (int mt = 0; mt < 2; ++mt)
#pragma unroll
    for (int nt = 0; nt < 2; ++nt) {
      acc0[mt][nt] = (f32x4){0.f, 0.f, 0.f, 0.f};
      acc1[mt][nt] = (f32x4){0.f, 0.f, 0.f, 0.f};
    }

  loadIter(0);
  for (int it = 0; it < 128; ++it) {
    __syncthreads();
    stash(a0, a1, Ah, Al);
    stash(b0, b1, Bh, Bl);
    stash(c0, c1, Ch, Cl);
    if (doK) {
      sK[0] += a0.x + a1.x; sK[1] += a0.y + a1.y;
      sK[2] += a0.z + a1.z; sK[3] += a0.w + a1.w;
    }
    if (doV) {
      sV[0] += c0.x + c1.x; sV[1] += c0.y + c1.y;
      sV[2] += c0.z + c1.z; sV[3] += c0.w + c1.w;
    }
    __syncthreads();
    if (it < 127) loadIter(it + 1);

    short8 bh[2], bl[2], ch[2], cl[2];
#pragma unroll
    for (int nt = 0; nt < 2; ++nt) {
      int rB = wc * 32 + nt * 16 + lrow;
      bh[nt] = *(const short8*)&Bh[rB][kof];
      bl[nt] = *(const short8*)&Bl[rB][kof];
      ch[nt] = *(const short8*)&Ch[rB][kof];
      cl[nt] = *(const short8*)&Cl[rB][kof];
    }
#pragma unroll
    for (int mt = 0; mt < 2; ++mt) {
      int rA = wr * 32 + mt * 16 + lrow;
      short8 ah = *(const short8*)&Ah[rA][kof];
      short8 al = *(const short8*)&Al[rA][kof];
#pragma unroll
      for (int nt = 0; nt < 2; ++nt) {
        f32x4 t = acc0[mt][nt];
        t = __builtin_amdgcn_mfma_f32_16x16x32_bf16(ah, bh[nt], t, 0, 0, 0);
        t = __builtin_amdgcn_mfma_f32_16x16x32_bf16(ah, bl[nt], t, 0, 0, 0);
        t = __builtin_amdgcn_mfma_f32_16x16x32_bf16(al, bh[nt], t, 0, 0, 0);
        t = __builtin_amdgcn_mfma_f32_16x16x32_bf16(al, bl[nt], t, 0, 0, 0);
        acc0[mt][nt] = t;
        f32x4 u = acc1[mt][nt];
        u = __builtin_amdgcn_mfma_f32_16x16x32_bf16(ah, ch[nt], u, 0, 0, 0);
        u = __builtin_amdgcn_mfma_f32_16x16x32_bf16(ah, cl[nt], u, 0, 0, 0);
        u = __builtin_amdgcn_mfma_f32_16x16x32_bf16(al, ch[nt], u, 0, 0, 0);
        u = __builtin_amdgcn_mfma_f32_16x16x32_bf16(al, cl[nt], u, 0, 0, 0);
        acc1[mt][nt] = u;
      }
    }
  }

  float* G0 = G + ((size_t)b * 2) * 65536;
  float* G1 = G0 + 65536;
#pragma unroll
  for (int mt = 0; mt < 2; ++mt)
#pragma unroll
    for (int nt = 0; nt < 2; ++nt)
#pragma unroll
      for (int r = 0; r < 4; ++r) {
        int row = mBase + wr * 32 + mt * 16 + (lane >> 4) * 4 + r;
        int col = nBase + wc * 32 + nt * 16 + (lane & 15);
        G0[(size_t)row * DDIM + col] = acc0[mt][nt][r];
        G1[(size_t)row * DDIM + col] = acc1[mt][nt][r];
      }

  if (doK) {
    __syncthreads();
#pragma unroll
    for (int i = 0; i < 4; ++i) red[fp][dbase + i] = sK[i];
    __syncthreads();
    if (tid < 64) {
      float t = 0.f;
      for (int c = 0; c < 16; ++c) t += red[c][tid];
      svec[(size_t)1 * 32 * 256 + (size_t)b * 256 + mBase + tid] = t;
    }
  }
  if (doV) {
    __syncthreads();
#pragma unroll
    for (int i = 0; i < 4; ++i) red[fp][dbase + i] = sV[i];
    __syncthreads();
    if (tid < 64) {
      float t = 0.f;
      for (int c = 0; c < 16; ++c) t += red[c][tid];
      svec[(size_t)2 * 32 * 256 + (size_t)b * 256 + nBase + tid] = t;
    }
  }
}

// ---------------- small vectors: uk=Wk sk, uv=Wv sv, qsum=Wq sq + F bq ------
__global__ void smallvec(const float* __restrict__ Wq, const float* __restrict__ bq,
                         const float* __restrict__ Wk, const float* __restrict__ Wv,
                         const float* __restrict__ svec, float* __restrict__ uvec) {
  int b = blockIdx.x; int d = threadIdx.x;
  __shared__ float sq[256], sk[256], sv[256];
  sq[d] = svec[((size_t)0 * 32 + b) * DDIM + d];
  sk[d] = svec[((size_t)1 * 32 + b) * DDIM + d];
  sv[d] = svec[((size_t)2 * 32 + b) * DDIM + d];
  __syncthreads();
  float uk = 0.f, uv = 0.f, uq = 0.f;
  for (int j = 0; j < 256; j += 4) {
    float4 wk4 = *(const float4*)(Wk + (size_t)d * DDIM + j);
    float4 wv4 = *(const float4*)(Wv + (size_t)d * DDIM + j);
    float4 wq4 = *(const float4*)(Wq + (size_t)d * DDIM + j);
    uk += wk4.x * sk[j] + wk4.y * sk[j + 1] + wk4.z * sk[j + 2] + wk4.w * sk[j + 3];
    uv += wv4.x * sv[j] + wv4.y * sv[j + 1] + wv4.z * sv[j + 2] + wv4.w * sv[j + 3];
    uq += wq4.x * sq[j] + wq4.y * sq[j + 1] + wq4.z * sq[j + 2] + wq4.w * sq[j + 3];
  }
  uvec[((size_t)0 * 32 + b) * DDIM + d] = uk;
  uvec[((size_t)1 * 32 + b) * DDIM + d] = uv;
  uvec[((size_t)2 * 32 + b) * DDIM + d] = uq + 4096.f * bq[d];
}

// ---------------- T[b][w] = Wk @ G[b][w]  (nn GEMM) ----------------
__global__ __launch_bounds__(256) void gemm_pass1(const float* __restrict__ Wk,
                                                  const float* __restrict__ G,
                                                  float* __restrict__ T) {
  int tile = blockIdx.x, w = blockIdx.y, b = blockIdx.z;
  int tm = tile >> 2, tn = tile & 3;
  const float* A = Wk;
  const float* B = G + ((size_t)b * 2 + w) * 65536;
  float* C = T + ((size_t)b * 2 + w) * 65536;
  __shared__ __align__(16) float As[16][64];
  __shared__ __align__(16) float Bs[16][64];
  int tid = threadIdx.x;
  int ty = tid >> 4, tx = tid & 15;
  int am = tid & 63, ak4 = tid >> 6;
  int brow = tid >> 4, bcol4 = tid & 15;
  int mBase = tm * 64, nBase = tn * 64;
  float acc[4][4];
#pragma unroll
  for (int i = 0; i < 4; i++)
#pragma unroll
    for (int j = 0; j < 4; j++) acc[i][j] = 0.f;
  for (int k0 = 0; k0 < 256; k0 += 16) {
    float4 a = *(const float4*)(A + (size_t)(mBase + am) * DDIM + k0 + ak4 * 4);
    float4 bb = *(const float4*)(B + (size_t)(k0 + brow) * DDIM + nBase + bcol4 * 4);
    __syncthreads();
    As[ak4 * 4 + 0][am] = a.x; As[ak4 * 4 + 1][am] = a.y;
    As[ak4 * 4 + 2][am] = a.z; As[ak4 * 4 + 3][am] = a.w;
    *(float4*)&Bs[brow][bcol4 * 4] = bb;
    __syncthreads();
#pragma unroll
    for (int kstep = 0; kstep < 16; ++kstep) {
      float4 a4 = *(const float4*)&As[kstep][ty * 4];
      float4 b4 = *(const float4*)&Bs[kstep][tx * 4];
      float av[4] = {a4.x, a4.y, a4.z, a4.w};
      float bvv[4] = {b4.x, b4.y, b4.z, b4.w};
#pragma unroll
      for (int i = 0; i < 4; i++)
#pragma unroll
        for (int j = 0; j < 4; j++)
          acc[i][j] = fmaf(av[i], bvv[j], acc[i][j]);
    }
  }
#pragma unroll
  for (int i = 0; i < 4; i++) {
    float4 o = make_float4(acc[i][0], acc[i][1], acc[i][2], acc[i][3]);
    *(float4*)(C + (size_t)(mBase + ty * 4 + i) * DDIM + nBase + tx * 4) = o;
  }
}

// ---------------- S[b][w] = T[b][w] @ W^T  (nt GEMM) ----------------
__global__ __launch_bounds__(256) void gemm_pass2(const float* __restrict__ T,
                                                  const float* __restrict__ Wk,
                                                  const float* __restrict__ Wv,
                                                  float* __restrict__ S) {
  int tile = blockIdx.x, w = blockIdx.y, b = blockIdx.z;
  int tm = tile >> 2, tn = tile & 3;
  const float* A = T + ((size_t)b * 2 + w) * 65536;
  const float* W = w ? Wv : Wk;
  float* C = S + ((size_t)b * 2 + w) * 65536;
  __shared__ __align__(16) float As[16][64];
  __shared__ __align__(16) float Bs[16][64];
  int tid = threadIdx.x;
  int ty = tid >> 4, tx = tid & 15;
  int am = tid & 63, ak4 = tid >> 6;
  int mBase = tm * 64, nBase = tn * 64;
  float acc[4][4];
#pragma unroll
  for (int i = 0; i < 4; i++)
#pragma unroll
    for (int j = 0; j < 4; j++) acc[i][j] = 0.f;
  for (int k0 = 0; k0 < 256; k0 += 16) {
    float4 a = *(const float4*)(A + (size_t)(mBase + am) * DDIM + k0 + ak4 * 4);
    float4 bb = *(const float4*)(W + (size_t)(nBase + am) * DDIM + k0 + ak4 * 4);
    __syncthreads();
    As[ak4 * 4 + 0][am] = a.x; As[ak4 * 4 + 1][am] = a.y;
    As[ak4 * 4 + 2][am] = a.z; As[ak4 * 4 + 3][am] = a.w;
    Bs[ak4 * 4 + 0][am] = bb.x; Bs[ak4 * 4 + 1][am] = bb.y;
    Bs[ak4 * 4 + 2][am] = bb.z; Bs[ak4 * 4 + 3][am] = bb.w;
    __syncthreads();
#pragma unroll
    for (int kstep = 0; kstep < 16; ++kstep) {
      float4 a4 = *(const float4*)&As[kstep][ty * 4];
      float4 b4 = *(const float4*)&Bs[kstep][tx * 4];
      float av[4] = {a4.x, a4.y, a4.z, a4.w};
      float bvv[4] = {b4.x, b4.y, b4.z, b4.w};
#pragma unroll
      for (int i = 0; i < 4; i++)
#pragma unroll
        for (int j = 0; j < 4; j++)
          acc[i][j] = fmaf(av[i], bvv[j], acc[i][j]);
    }
  }
#pragma unroll
  for (int i = 0; i < 4; i++) {
    float4 o = make_float4(acc[i][0], acc[i][1], acc[i][2], acc[i][3]);
    *(float4*)(C + (size_t)(mBase + ty * 4 + i) * DDIM + nBase + tx * 4) = o;
  }
}

// ---------------- rank-1 bias terms + alpha*I ----------------
__global__ void rank1(float* __restrict__ S, const float* __restrict__ uvec,
                      const float* __restrict__ bk, const float* __restrict__ bv) {
  int d = blockIdx.x, w = blockIdx.y, b = blockIdx.z;
  int e = threadIdx.x;
  float* row = S + (((size_t)b * 2 + w) * DDIM + d) * DDIM;
  float ukd = uvec[((size_t)0 * 32 + b) * DDIM + d];
  float bkd = bk[d];
  if (w == 0) {
    float uke = uvec[((size_t)0 * 32 + b) * DDIM + e];
    float add = ukd * bk[e] + bkd * uke + 4096.f * bkd * bk[e] + ((d == e) ? ALPHA_R : 0.f);
    row[e] += add;
  } else {
    float uve = uvec[((size_t)1 * 32 + b) * DDIM + e];
    float add = ukd * bv[e] + bkd * uve + 4096.f * bkd * bv[e];
    row[e] += add;
  }
}

// ---------------- blocked Gauss-Jordan solve (same as R3) ----------------
__global__ __launch_bounds__(1024, 4) void gj_solve(float* __restrict__ Sb) {
  int b = blockIdx.x;
  float* A  = Sb + (size_t)b * 2 * 65536;
  float* Bm = A + 65536;
  int tid = threadIdx.x;
  int r = tid >> 2;
  int q = tid & 3;

  __shared__ __align__(16) float Mt[64][264];
  __shared__ __align__(16) float Sst[64][260];
  __shared__ __align__(16) float prow[64];
  __shared__ float fac[256];

  for (int pg = 0; pg < 4; ++pg) {
    float x[16];
    {
      const float* Ar = A + (size_t)r * 256 + pg * 64 + q * 16;
#pragma unroll
      for (int m = 0; m < 4; ++m) {
        float4 t = *(const float4*)(Ar + m * 4);
        x[m * 4 + 0] = t.x; x[m * 4 + 1] = t.y;
        x[m * 4 + 2] = t.z; x[m * 4 + 3] = t.w;
      }
    }
#pragma unroll
    for (int jo = 0; jo < 4; ++jo) {
#pragma unroll
      for (int ji = 0; ji < 16; ++ji) {
        const int j = jo * 16 + ji;
        const int p = pg * 64 + j;
        if (r == p) {
          *(float4*)&prow[q * 16 + 0]  = make_float4(x[0], x[1], x[2], x[3]);
          *(float4*)&prow[q * 16 + 4]  = make_float4(x[4], x[5], x[6], x[7]);
          *(float4*)&prow[q * 16 + 8]  = make_float4(x[8], x[9], x[10], x[11]);
          *(float4*)&prow[q * 16 + 12] = make_float4(x[12], x[13], x[14], x[15]);
        }
        if (q == jo) fac[r] = x[ji];
        __syncthreads();
        float piv = fac[p];
        float ip = 1.0f / piv;
        float f = fac[r];
        float g = f * ip;
        bool diag = (r == p);
#pragma unroll
        for (int m = 0; m < 16; ++m) {
          float pv = prow[q * 16 + m];
          x[m] = diag ? pv * ip : fmaf(-g, pv, x[m]);
        }
        if (q == jo) x[ji] = diag ? ip : (0.f - g);
        __syncthreads();
      }
    }
#pragma unroll
    for (int m = 0; m < 16; ++m) Mt[q * 16 + m][r] = x[m];
    __syncthreads();

    for (int chunk = 0; chunk < 2; ++chunk) {
      int W, c_off; float* Csrc;
      if (chunk == 0) {
        W = (3 - pg) * 64; c_off = (pg + 1) * 64; Csrc = A;
        if (W == 0) continue;
      } else {
        W = 256; c_off = 0; Csrc = Bm;
      }
      {
        int cpt = W >> 4;
        int jr = tid >> 4, tc = tid & 15;
        const float* src = Csrc + (size_t)(pg * 64 + jr) * 256 + c_off + tc * cpt;
        for (int m = 0; m < cpt; m += 4) {
          float4 t = *(const float4*)(src + m);
          *(float4*)&Sst[jr][tc * cpt + m] = t;
        }
      }
      __syncthreads();
      int colTiles = W >> 3;
      int rt = tid / colTiles;
      int ctile = tid - rt * colTiles;
      if (rt < 32) {
        int r0 = rt * 8, c0 = ctile * 8;
        float acc[8][8];
#pragma unroll
        for (int i = 0; i < 8; ++i)
#pragma unroll
          for (int j2 = 0; j2 < 8; ++j2) acc[i][j2] = 0.f;
        for (int j = 0; j < 64; ++j) {
          float4 m0 = *(const float4*)&Mt[j][r0];
          float4 m1 = *(const float4*)&Mt[j][r0 + 4];
          float4 s0 = *(const float4*)&Sst[j][c0];
          float4 s1 = *(const float4*)&Sst[j][c0 + 4];
          float mv[8] = {m0.x, m0.y, m0.z, m0.w, m1.x, m1.y, m1.z, m1.w};
          float sv[8] = {s0.x, s0.y, s0.z, s0.w, s1.x, s1.y, s1.z, s1.w};
#pragma unroll
          for (int i = 0; i < 8; ++i)
#pragma unroll
            for (int j2 = 0; j2 < 8; ++j2)
              acc[i][j2] = fmaf(mv[i], sv[j2], acc[i][j2]);
        }
#pragma unroll
        for (int ii = 0; ii < 8; ++ii) {
          int row = r0 + ii;
          bool inPanel = ((row >> 6) == pg);
          float* dst = Csrc + (size_t)row * 256 + c_off + c0;
          float4 o0 = make_float4(acc[ii][0], acc[ii][1], acc[ii][2], acc[ii][3]);
          float4 o1 = make_float4(acc[ii][4], acc[ii][5], acc[ii][6], acc[ii][7]);
          if (!inPanel) {
            float4 a0 = *(const float4*)(dst);
            float4 a1 = *(const float4*)(dst + 4);
            o0.x += a0.x; o0.y += a0.y; o0.z += a0.z; o0.w += a0.w;
            o1.x += a1.x; o1.y += a1.y; o1.z += a1.z; o1.w += a1.w;
          }
          *(float4*)(dst) = o0;
          *(float4*)(dst + 4) = o1;
        }
      }
      __syncthreads();
    }
  }
}

// ---------------- row softmax stats (max, sumexp) over X rows ----------------
__global__ void rowstats(const float* __restrict__ S, float* __restrict__ stats) {
  int b = blockIdx.x;
  const float* X = S + ((size_t)b * 2 + 1) * 65536;
  int tid = threadIdx.x; int lane = tid & 63; int wv = tid >> 6;
  for (int rr = 0; rr < 64; ++rr) {
    int row = rr * 4 + wv;
    float x0 = X[row * 256 + lane];
    float x1 = X[row * 256 + lane + 64];
    float x2 = X[row * 256 + lane + 128];
    float x3 = X[row * 256 + lane + 192];
    float m = fmaxf(fmaxf(x0, x1), fmaxf(x2, x3));
    for (int o = 32; o > 0; o >>= 1) m = fmaxf(m, __shfl_xor(m, o, 64));
    float s = expf(x0 - m) + expf(x1 - m) + expf(x2 - m) + expf(x3 - m);
    for (int o = 32; o > 0; o >>= 1) s += __shfl_xor(s, o, 64);
    if (lane == 0) {
      stats[((size_t)b * 256 + row) * 2 + 0] = m;
      stats[((size_t)b * 256 + row) * 2 + 1] = s;
    }
  }
}

// ---------------- h[b,e] = sum_d qsum[b,d] * softmax(X[b,d,:])[e] ----------
__global__ void final_h(const float* __restrict__ S, const float* __restrict__ stats,
                        const float* __restrict__ uvec, float* __restrict__ out) {
  int b = blockIdx.x; int e = threadIdx.x;
  const float* X = S + ((size_t)b * 2 + 1) * 65536;
  const float* qs = uvec + ((size_t)2 * 32 + b) * DDIM;
  float acc = 0.f;
  for (int d = 0; d < 256; ++d) {
    float m = stats[((size_t)b * 256 + d) * 2 + 0];
    float s = stats[((size_t)b * 256 + d) * 2 + 1];
    acc += qs[d] * expf(X[d * 256 + e] - m) / s;
  }
  out[(size_t)b * 256 + e] = acc;
}

extern "C" void kernel_launch(void* const* d_in, const int* in_sizes, int n_in,
                              void* d_out, int out_size, void* d_ws, size_t ws_size,
                              hipStream_t stream) {
  const float* q  = (const float*)d_in[0];
  const float* k  = (const float*)d_in[1];
  const float* v  = (const float*)d_in[2];
  const float* Wq = (const float*)d_in[3];
  const float* bq = (const float*)d_in[4];
  const float* Wk = (const float*)d_in[5];
  const float* bk = (const float*)d_in[6];
  const float* Wv = (const float*)d_in[7];
  const float* bv = (const float*)d_in[8];
  float* out = (float*)d_out;

  float* ws   = (float*)d_ws;
  float* Gbuf = ws;                                    // [32][2][256][256]
  float* Tbuf = Gbuf + (size_t)32 * 2 * 65536;         // [32][2][256][256]
  float* Sbuf = Tbuf + (size_t)32 * 2 * 65536;         // [32][2][256][256] (A, B->X)
  float* part = Sbuf + (size_t)32 * 2 * 65536;         // [16][32][256] (q partials)
  float* svec = part + (size_t)16 * 3 * 32 * 256;      // [3][32][256]
  float* uvec = svec + (size_t)3 * 32 * 256;           // [3][32][256]
  float* stats = uvec + (size_t)3 * 32 * 256;          // [32][256][2]

  colsum_partial_q<<<dim3(16, 32), 256, 0, stream>>>(q, part);
  colsum_reduce_q<<<32, 256, 0, stream>>>(part, svec);
  gram_mfma<<<512, 256, 0, stream>>>(k, v, Gbuf, svec);
  smallvec<<<32, 256, 0, stream>>>(Wq, bq, Wk, Wv, svec, uvec);
  gemm_pass1<<<dim3(16, 2, 32), 256, 0, stream>>>(Wk, Gbuf, Tbuf);
  gemm_pass2<<<dim3(16, 2, 32), 256, 0, stream>>>(Tbuf, Wk, Wv, Sbuf);
  rank1<<<dim3(256, 2, 32), 256, 0, stream>>>(Sbuf, uvec, bk, bv);
  gj_solve<<<32, 1024, 0, stream>>>(Sbuf);
  rowstats<<<32, 256, 0, stream>>>(Sbuf, stats);
  final_h<<<32, 256, 0, stream>>>(Sbuf, stats, uvec, out);
}

// Round 5
// 627.146 us; speedup vs baseline: 11.7286x; 1.1688x over previous
//
#include <hip/hip_runtime.h>
#include <math.h>

#define FDIM 4096
#define DDIM 256
#define ALPHA_R 0.001f

typedef __attribute__((ext_vector_type(8))) short short8;
typedef __attribute__((ext_vector_type(4))) float f32x4;

__device__ __forceinline__ unsigned cvt_pk_bf16(float lo_e, float hi_e) {
  unsigned r;
  asm("v_cvt_pk_bf16_f32 %0, %1, %2" : "=v"(r) : "v"(lo_e), "v"(hi_e));
  return r;
}

// ---------------- column sums for q only ----------------
__global__ void colsum_partial_q(const float* __restrict__ q,
                                 float* __restrict__ part) {
  int chunk = blockIdx.x;   // 16
  int b     = blockIdx.y;   // 32
  int d = threadIdx.x;
  const float* p = q + ((size_t)b * FDIM + chunk * 256) * DDIM + d;
  float s = 0.f;
  for (int i = 0; i < 256; ++i) s += p[(size_t)i * DDIM];
  part[((size_t)chunk * 32 + b) * DDIM + d] = s;
}

__global__ void colsum_reduce_q(const float* __restrict__ part,
                                float* __restrict__ svec) {
  int b = blockIdx.x; int d = threadIdx.x;
  float s = 0.f;
  for (int c = 0; c < 16; ++c) s += part[((size_t)c * 32 + b) * DDIM + d];
  svec[(size_t)b * DDIM + d] = s;   // svec[0][b][d]
}

// ---------------- MFMA Gram: G[b][0]=k^T k, G[b][1]=k^T v (bf16 hi/lo, 3-term)
// Staging is transpose-free: lane <-> one d-row of the tile (64 lanes = 64
// rows), wave <-> 8-f slice. 8 scalar dword loads per stream per lane (each
// wave-instr = 256B contiguous), local cvt to 4 hi + 4 lo dwords, ONE b128
// write per array at own row -> 2-way banks (free). Frag reads b128, 2-way.
__global__ __launch_bounds__(256) void gram_mfma(const float* __restrict__ kg,
                                                 const float* __restrict__ vg,
                                                 float* __restrict__ G,
                                                 float* __restrict__ svec) {
  int flat = blockIdx.x;            // 512
  int xcd = flat & 7, s = flat >> 3;
  int b = xcd * 4 + (s >> 4);       // 4 batches per XCD
  int tile = s & 15;
  int tm = tile >> 2, tn = tile & 3;
  int mBase = tm * 64, nBase = tn * 64;
  const float* Kb = kg + (size_t)b * FDIM * DDIM;
  const float* Vb = vg + (size_t)b * FDIM * DDIM;

  __shared__ __align__(16) unsigned short Ah[64][40], Al[64][40];
  __shared__ __align__(16) unsigned short Bh[64][40], Bl[64][40];
  __shared__ __align__(16) unsigned short Ch[64][40], Cl[64][40];
  __shared__ float sred[4][68];

  int tid = threadIdx.x;
  int w = tid >> 6, lane = tid & 63;
  int wr = w >> 1, wc = w & 1;
  int lrow = lane & 15;
  int kof = (lane >> 4) * 8;        // ushort col of fragment

  const float* pA = Kb + mBase + lane;
  const float* pB = Kb + nBase + lane;
  const float* pC = Vb + nBase + lane;

  bool doK = (tn == 0), doV = (tm == 0);
  float sK = 0.f, sV = 0.f;

  float xa[8], xb[8], xc[8];
  auto loadIter = [&](int it) {
    int f = it * 32 + w * 8;
#pragma unroll
    for (int j = 0; j < 8; ++j) {
      xa[j] = pA[(size_t)(f + j) * DDIM];
      xb[j] = pB[(size_t)(f + j) * DDIM];
      xc[j] = pC[(size_t)(f + j) * DDIM];
    }
  };
  auto stash = [&](const float* x, unsigned short (*H)[40], unsigned short (*L)[40]) {
    unsigned h0 = cvt_pk_bf16(x[0], x[1]);
    unsigned h1 = cvt_pk_bf16(x[2], x[3]);
    unsigned h2 = cvt_pk_bf16(x[4], x[5]);
    unsigned h3 = cvt_pk_bf16(x[6], x[7]);
    unsigned l0 = cvt_pk_bf16(x[0] - __uint_as_float(h0 << 16),
                              x[1] - __uint_as_float(h0 & 0xFFFF0000u));
    unsigned l1 = cvt_pk_bf16(x[2] - __uint_as_float(h1 << 16),
                              x[3] - __uint_as_float(h1 & 0xFFFF0000u));
    unsigned l2 = cvt_pk_bf16(x[4] - __uint_as_float(h2 << 16),
                              x[5] - __uint_as_float(h2 & 0xFFFF0000u));
    unsigned l3 = cvt_pk_bf16(x[6] - __uint_as_float(h3 << 16),
                              x[7] - __uint_as_float(h3 & 0xFFFF0000u));
    *(uint4*)&H[lane][w * 8] = make_uint4(h0, h1, h2, h3);
    *(uint4*)&L[lane][w * 8] = make_uint4(l0, l1, l2, l3);
  };

  f32x4 acc0[2][2], acc1[2][2];
#pragma unroll
  for (int mt = 0; mt < 2; ++mt)
#pragma unroll
    for (int nt = 0; nt < 2; ++nt) {
      acc0[mt][nt] = (f32x4){0.f, 0.f, 0.f, 0.f};
      acc1[mt][nt] = (f32x4){0.f, 0.f, 0.f, 0.f};
    }

  loadIter(0);
  for (int it = 0; it < 128; ++it) {
    __syncthreads();
    stash(xa, Ah, Al);
    stash(xb, Bh, Bl);
    stash(xc, Ch, Cl);
    if (doK) sK += ((xa[0] + xa[1]) + (xa[2] + xa[3])) + ((xa[4] + xa[5]) + (xa[6] + xa[7]));
    if (doV) sV += ((xc[0] + xc[1]) + (xc[2] + xc[3])) + ((xc[4] + xc[5]) + (xc[6] + xc[7]));
    __syncthreads();
    if (it < 127) loadIter(it + 1);

    short8 bh[2], bl[2], ch[2], cl[2];
#pragma unroll
    for (int nt = 0; nt < 2; ++nt) {
      int rB = wc * 32 + nt * 16 + lrow;
      bh[nt] = *(const short8*)&Bh[rB][kof];
      bl[nt] = *(const short8*)&Bl[rB][kof];
      ch[nt] = *(const short8*)&Ch[rB][kof];
      cl[nt] = *(const short8*)&Cl[rB][kof];
    }
    __builtin_amdgcn_s_setprio(1);
#pragma unroll
    for (int mt = 0; mt < 2; ++mt) {
      int rA = wr * 32 + mt * 16 + lrow;
      short8 ah = *(const short8*)&Ah[rA][kof];
      short8 al = *(const short8*)&Al[rA][kof];
#pragma unroll
      for (int nt = 0; nt < 2; ++nt) {
        f32x4 t = acc0[mt][nt];
        t = __builtin_amdgcn_mfma_f32_16x16x32_bf16(ah, bh[nt], t, 0, 0, 0);
        t = __builtin_amdgcn_mfma_f32_16x16x32_bf16(ah, bl[nt], t, 0, 0, 0);
        t = __builtin_amdgcn_mfma_f32_16x16x32_bf16(al, bh[nt], t, 0, 0, 0);
        acc0[mt][nt] = t;
        f32x4 u = acc1[mt][nt];
        u = __builtin_amdgcn_mfma_f32_16x16x32_bf16(ah, ch[nt], u, 0, 0, 0);
        u = __builtin_amdgcn_mfma_f32_16x16x32_bf16(ah, cl[nt], u, 0, 0, 0);
        u = __builtin_amdgcn_mfma_f32_16x16x32_bf16(al, ch[nt], u, 0, 0, 0);
        acc1[mt][nt] = u;
      }
    }
    __builtin_amdgcn_s_setprio(0);
  }

  float* G0 = G + ((size_t)b * 2) * 65536;
  float* G1 = G0 + 65536;
#pragma unroll
  for (int mt = 0; mt < 2; ++mt)
#pragma unroll
    for (int nt = 0; nt < 2; ++nt)
#pragma unroll
      for (int r = 0; r < 4; ++r) {
        int row = mBase + wr * 32 + mt * 16 + (lane >> 4) * 4 + r;
        int col = nBase + wc * 32 + nt * 16 + (lane & 15);
        G0[(size_t)row * DDIM + col] = acc0[mt][nt][r];
        G1[(size_t)row * DDIM + col] = acc1[mt][nt][r];
      }

  if (doK) {
    __syncthreads();
    sred[w][lane] = sK;
    __syncthreads();
    if (tid < 64) {
      float t = sred[0][tid] + sred[1][tid] + sred[2][tid] + sred[3][tid];
      svec[(size_t)1 * 32 * 256 + (size_t)b * 256 + mBase + tid] = t;
    }
  }
  if (doV) {
    __syncthreads();
    sred[w][lane] = sV;
    __syncthreads();
    if (tid < 64) {
      float t = sred[0][tid] + sred[1][tid] + sred[2][tid] + sred[3][tid];
      svec[(size_t)2 * 32 * 256 + (size_t)b * 256 + nBase + tid] = t;
    }
  }
}

// ---------------- small vectors: uk=Wk sk, uv=Wv sv, qsum=Wq sq + F bq ------
__global__ void smallvec(const float* __restrict__ Wq, const float* __restrict__ bq,
                         const float* __restrict__ Wk, const float* __restrict__ Wv,
                         const float* __restrict__ svec, float* __restrict__ uvec) {
  int b = blockIdx.x; int d = threadIdx.x;
  __shared__ float sq[256], sk[256], sv[256];
  sq[d] = svec[((size_t)0 * 32 + b) * DDIM + d];
  sk[d] = svec[((size_t)1 * 32 + b) * DDIM + d];
  sv[d] = svec[((size_t)2 * 32 + b) * DDIM + d];
  __syncthreads();
  float uk = 0.f, uv = 0.f, uq = 0.f;
  for (int j = 0; j < 256; j += 4) {
    float4 wk4 = *(const float4*)(Wk + (size_t)d * DDIM + j);
    float4 wv4 = *(const float4*)(Wv + (size_t)d * DDIM + j);
    float4 wq4 = *(const float4*)(Wq + (size_t)d * DDIM + j);
    uk += wk4.x * sk[j] + wk4.y * sk[j + 1] + wk4.z * sk[j + 2] + wk4.w * sk[j + 3];
    uv += wv4.x * sv[j] + wv4.y * sv[j + 1] + wv4.z * sv[j + 2] + wv4.w * sv[j + 3];
    uq += wq4.x * sq[j] + wq4.y * sq[j + 1] + wq4.z * sq[j + 2] + wq4.w * sq[j + 3];
  }
  uvec[((size_t)0 * 32 + b) * DDIM + d] = uk;
  uvec[((size_t)1 * 32 + b) * DDIM + d] = uv;
  uvec[((size_t)2 * 32 + b) * DDIM + d] = uq + 4096.f * bq[d];
}

// ---------------- T[b][w] = Wk @ G[b][w]  (nn GEMM) ----------------
__global__ __launch_bounds__(256) void gemm_pass1(const float* __restrict__ Wk,
                                                  const float* __restrict__ G,
                                                  float* __restrict__ T) {
  int tile = blockIdx.x, w = blockIdx.y, b = blockIdx.z;
  int tm = tile >> 2, tn = tile & 3;
  const float* A = Wk;
  const float* B = G + ((size_t)b * 2 + w) * 65536;
  float* C = T + ((size_t)b * 2 + w) * 65536;
  __shared__ __align__(16) float As[16][64];
  __shared__ __align__(16) float Bs[16][64];
  int tid = threadIdx.x;
  int ty = tid >> 4, tx = tid & 15;
  int am = tid & 63, ak4 = tid >> 6;
  int brow = tid >> 4, bcol4 = tid & 15;
  int mBase = tm * 64, nBase = tn * 64;
  float acc[4][4];
#pragma unroll
  for (int i = 0; i < 4; i++)
#pragma unroll
    for (int j = 0; j < 4; j++) acc[i][j] = 0.f;
  for (int k0 = 0; k0 < 256; k0 += 16) {
    float4 a = *(const float4*)(A + (size_t)(mBase + am) * DDIM + k0 + ak4 * 4);
    float4 bb = *(const float4*)(B + (size_t)(k0 + brow) * DDIM + nBase + bcol4 * 4);
    __syncthreads();
    As[ak4 * 4 + 0][am] = a.x; As[ak4 * 4 + 1][am] = a.y;
    As[ak4 * 4 + 2][am] = a.z; As[ak4 * 4 + 3][am] = a.w;
    *(float4*)&Bs[brow][bcol4 * 4] = bb;
    __syncthreads();
#pragma unroll
    for (int kstep = 0; kstep < 16; ++kstep) {
      float4 a4 = *(const float4*)&As[kstep][ty * 4];
      float4 b4 = *(const float4*)&Bs[kstep][tx * 4];
      float av[4] = {a4.x, a4.y, a4.z, a4.w};
      float bvv[4] = {b4.x, b4.y, b4.z, b4.w};
#pragma unroll
      for (int i = 0; i < 4; i++)
#pragma unroll
        for (int j = 0; j < 4; j++)
          acc[i][j] = fmaf(av[i], bvv[j], acc[i][j]);
    }
  }
#pragma unroll
  for (int i = 0; i < 4; i++) {
    float4 o = make_float4(acc[i][0], acc[i][1], acc[i][2], acc[i][3]);
    *(float4*)(C + (size_t)(mBase + ty * 4 + i) * DDIM + nBase + tx * 4) = o;
  }
}

// ---------------- S[b][w] = T[b][w] @ W^T  (nt GEMM) ----------------
__global__ __launch_bounds__(256) void gemm_pass2(const float* __restrict__ T,
                                                  const float* __restrict__ Wk,
                                                  const float* __restrict__ Wv,
                                                  float* __restrict__ S) {
  int tile = blockIdx.x, w = blockIdx.y, b = blockIdx.z;
  int tm = tile >> 2, tn = tile & 3;
  const float* A = T + ((size_t)b * 2 + w) * 65536;
  const float* W = w ? Wv : Wk;
  float* C = S + ((size_t)b * 2 + w) * 65536;
  __shared__ __align__(16) float As[16][64];
  __shared__ __align__(16) float Bs[16][64];
  int tid = threadIdx.x;
  int ty = tid >> 4, tx = tid & 15;
  int am = tid & 63, ak4 = tid >> 6;
  int mBase = tm * 64, nBase = tn * 64;
  float acc[4][4];
#pragma unroll
  for (int i = 0; i < 4; i++)
#pragma unroll
    for (int j = 0; j < 4; j++) acc[i][j] = 0.f;
  for (int k0 = 0; k0 < 256; k0 += 16) {
    float4 a = *(const float4*)(A + (size_t)(mBase + am) * DDIM + k0 + ak4 * 4);
    float4 bb = *(const float4*)(W + (size_t)(nBase + am) * DDIM + k0 + ak4 * 4);
    __syncthreads();
    As[ak4 * 4 + 0][am] = a.x; As[ak4 * 4 + 1][am] = a.y;
    As[ak4 * 4 + 2][am] = a.z; As[ak4 * 4 + 3][am] = a.w;
    Bs[ak4 * 4 + 0][am] = bb.x; Bs[ak4 * 4 + 1][am] = bb.y;
    Bs[ak4 * 4 + 2][am] = bb.z; Bs[ak4 * 4 + 3][am] = bb.w;
    __syncthreads();
#pragma unroll
    for (int kstep = 0; kstep < 16; ++kstep) {
      float4 a4 = *(const float4*)&As[kstep][ty * 4];
      float4 b4 = *(const float4*)&Bs[kstep][tx * 4];
      float av[4] = {a4.x, a4.y, a4.z, a4.w};
      float bvv[4] = {b4.x, b4.y, b4.z, b4.w};
#pragma unroll
      for (int i = 0; i < 4; i++)
#pragma unroll
        for (int j = 0; j < 4; j++)
          acc[i][j] = fmaf(av[i], bvv[j], acc[i][j]);
    }
  }
#pragma unroll
  for (int i = 0; i < 4; i++) {
    float4 o = make_float4(acc[i][0], acc[i][1], acc[i][2], acc[i][3]);
    *(float4*)(C + (size_t)(mBase + ty * 4 + i) * DDIM + nBase + tx * 4) = o;
  }
}

// ---------------- rank-1 bias terms + alpha*I ----------------
__global__ void rank1(float* __restrict__ S, const float* __restrict__ uvec,
                      const float* __restrict__ bk, const float* __restrict__ bv) {
  int d = blockIdx.x, w = blockIdx.y, b = blockIdx.z;
  int e = threadIdx.x;
  float* row = S + (((size_t)b * 2 + w) * DDIM + d) * DDIM;
  float ukd = uvec[((size_t)0 * 32 + b) * DDIM + d];
  float bkd = bk[d];
  if (w == 0) {
    float uke = uvec[((size_t)0 * 32 + b) * DDIM + e];
    float add = ukd * bk[e] + bkd * uke + 4096.f * bkd * bk[e] + ((d == e) ? ALPHA_R : 0.f);
    row[e] += add;
  } else {
    float uve = uvec[((size_t)1 * 32 + b) * DDIM + e];
    float add = ukd * bv[e] + bkd * uve + 4096.f * bkd * bv[e];
    row[e] += add;
  }
}

// ---------------- blocked Gauss-Jordan solve (same as R3) ----------------
__global__ __launch_bounds__(1024, 4) void gj_solve(float* __restrict__ Sb) {
  int b = blockIdx.x;
  float* A  = Sb + (size_t)b * 2 * 65536;
  float* Bm = A + 65536;
  int tid = threadIdx.x;
  int r = tid >> 2;
  int q = tid & 3;

  __shared__ __align__(16) float Mt[64][264];
  __shared__ __align__(16) float Sst[64][260];
  __shared__ __align__(16) float prow[64];
  __shared__ float fac[256];

  for (int pg = 0; pg < 4; ++pg) {
    float x[16];
    {
      const float* Ar = A + (size_t)r * 256 + pg * 64 + q * 16;
#pragma unroll
      for (int m = 0; m < 4; ++m) {
        float4 t = *(const float4*)(Ar + m * 4);
        x[m * 4 + 0] = t.x; x[m * 4 + 1] = t.y;
        x[m * 4 + 2] = t.z; x[m * 4 + 3] = t.w;
      }
    }
#pragma unroll
    for (int jo = 0; jo < 4; ++jo) {
#pragma unroll
      for (int ji = 0; ji < 16; ++ji) {
        const int j = jo * 16 + ji;
        const int p = pg * 64 + j;
        if (r == p) {
          *(float4*)&prow[q * 16 + 0]  = make_float4(x[0], x[1], x[2], x[3]);
          *(float4*)&prow[q * 16 + 4]  = make_float4(x[4], x[5], x[6], x[7]);
          *(float4*)&prow[q * 16 + 8]  = make_float4(x[8], x[9], x[10], x[11]);
          *(float4*)&prow[q * 16 + 12] = make_float4(x[12], x[13], x[14], x[15]);
        }
        if (q == jo) fac[r] = x[ji];
        __syncthreads();
        float piv = fac[p];
        float ip = 1.0f / piv;
        float f = fac[r];
        float g = f * ip;
        bool diag = (r == p);
#pragma unroll
        for (int m = 0; m < 16; ++m) {
          float pv = prow[q * 16 + m];
          x[m] = diag ? pv * ip : fmaf(-g, pv, x[m]);
        }
        if (q == jo) x[ji] = diag ? ip : (0.f - g);
        __syncthreads();
      }
    }
#pragma unroll
    for (int m = 0; m < 16; ++m) Mt[q * 16 + m][r] = x[m];
    __syncthreads();

    for (int chunk = 0; chunk < 2; ++chunk) {
      int W, c_off; float* Csrc;
      if (chunk == 0) {
        W = (3 - pg) * 64; c_off = (pg + 1) * 64; Csrc = A;
        if (W == 0) continue;
      } else {
        W = 256; c_off = 0; Csrc = Bm;
      }
      {
        int cpt = W >> 4;
        int jr = tid >> 4, tc = tid & 15;
        const float* src = Csrc + (size_t)(pg * 64 + jr) * 256 + c_off + tc * cpt;
        for (int m = 0; m < cpt; m += 4) {
          float4 t = *(const float4*)(src + m);
          *(float4*)&Sst[jr][tc * cpt + m] = t;
        }
      }
      __syncthreads();
      int colTiles = W >> 3;
      int rt = tid / colTiles;
      int ctile = tid - rt * colTiles;
      if (rt < 32) {
        int r0 = rt * 8, c0 = ctile * 8;
        float acc[8][8];
#pragma unroll
        for (int i = 0; i < 8; ++i)
#pragma unroll
          for (int j2 = 0; j2 < 8; ++j2) acc[i][j2] = 0.f;
        for (int j = 0; j < 64; ++j) {
          float4 m0 = *(const float4*)&Mt[j][r0];
          float4 m1 = *(const float4*)&Mt[j][r0 + 4];
          float4 s0 = *(const float4*)&Sst[j][c0];
          float4 s1 = *(const float4*)&Sst[j][c0 + 4];
          float mv[8] = {m0.x, m0.y, m0.z, m0.w, m1.x, m1.y, m1.z, m1.w};
          float sv[8] = {s0.x, s0.y, s0.z, s0.w, s1.x, s1.y, s1.z, s1.w};
#pragma unroll
          for (int i = 0; i < 8; ++i)
#pragma unroll
            for (int j2 = 0; j2 < 8; ++j2)
              acc[i][j2] = fmaf(mv[i], sv[j2], acc[i][j2]);
        }
#pragma unroll
        for (int ii = 0; ii < 8; ++ii) {
          int row = r0 + ii;
          bool inPanel = ((row >> 6) == pg);
          float* dst = Csrc + (size_t)row * 256 + c_off + c0;
          float4 o0 = make_float4(acc[ii][0], acc[ii][1], acc[ii][2], acc[ii][3]);
          float4 o1 = make_float4(acc[ii][4], acc[ii][5], acc[ii][6], acc[ii][7]);
          if (!inPanel) {
            float4 a0 = *(const float4*)(dst);
            float4 a1 = *(const float4*)(dst + 4);
            o0.x += a0.x; o0.y += a0.y; o0.z += a0.z; o0.w += a0.w;
            o1.x += a1.x; o1.y += a1.y; o1.z += a1.z; o1.w += a1.w;
          }
          *(float4*)(dst) = o0;
          *(float4*)(dst + 4) = o1;
        }
      }
      __syncthreads();
    }
  }
}

// ---------------- row softmax stats (max, sumexp) over X rows ----------------
__global__ void rowstats(const float* __restrict__ S, float* __restrict__ stats) {
  int b = blockIdx.x;
  const float* X = S + ((size_t)b * 2 + 1) * 65536;
  int tid = threadIdx.x; int lane = tid & 63; int wv = tid >> 6;
  for (int rr = 0; rr < 64; ++rr) {
    int row = rr * 4 + wv;
    float x0 = X[row * 256 + lane];
    float x1 = X[row * 256 + lane + 64];
    float x2 = X[row * 256 + lane + 128];
    float x3 = X[row * 256 + lane + 192];
    float m = fmaxf(fmaxf(x0, x1), fmaxf(x2, x3));
    for (int o = 32; o > 0; o >>= 1) m = fmaxf(m, __shfl_xor(m, o, 64));
    float s = expf(x0 - m) + expf(x1 - m) + expf(x2 - m) + expf(x3 - m);
    for (int o = 32; o > 0; o >>= 1) s += __shfl_xor(s, o, 64);
    if (lane == 0) {
      stats[((size_t)b * 256 + row) * 2 + 0] = m;
      stats[((size_t)b * 256 + row) * 2 + 1] = s;
    }
  }
}

// ---------------- h[b,e] = sum_d qsum[b,d] * softmax(X[b,d,:])[e] ----------
__global__ void final_h(const float* __restrict__ S, const float* __restrict__ stats,
                        const float* __restrict__ uvec, float* __restrict__ out) {
  int b = blockIdx.x; int e = threadIdx.x;
  const float* X = S + ((size_t)b * 2 + 1) * 65536;
  const float* qs = uvec + ((size_t)2 * 32 + b) * DDIM;
  float acc = 0.f;
  for (int d = 0; d < 256; ++d) {
    float m = stats[((size_t)b * 256 + d) * 2 + 0];
    float s = stats[((size_t)b * 256 + d) * 2 + 1];
    acc += qs[d] * expf(X[d * 256 + e] - m) / s;
  }
  out[(size_t)b * 256 + e] = acc;
}

extern "C" void kernel_launch(void* const* d_in, const int* in_sizes, int n_in,
                              void* d_out, int out_size, void* d_ws, size_t ws_size,
                              hipStream_t stream) {
  const float* q  = (const float*)d_in[0];
  const float* k  = (const float*)d_in[1];
  const float* v  = (const float*)d_in[2];
  const float* Wq = (const float*)d_in[3];
  const float* bq = (const float*)d_in[4];
  const float* Wk = (const float*)d_in[5];
  const float* bk = (const float*)d_in[6];
  const float* Wv = (const float*)d_in[7];
  const float* bv = (const float*)d_in[8];
  float* out = (float*)d_out;

  float* ws   = (float*)d_ws;
  float* Gbuf = ws;                                    // [32][2][256][256]
  float* Tbuf = Gbuf + (size_t)32 * 2 * 65536;         // [32][2][256][256]
  float* Sbuf = Tbuf + (size_t)32 * 2 * 65536;         // [32][2][256][256] (A, B->X)
  float* part = Sbuf + (size_t)32 * 2 * 65536;         // [16][32][256] (q partials)
  float* svec = part + (size_t)16 * 3 * 32 * 256;      // [3][32][256]
  float* uvec = svec + (size_t)3 * 32 * 256;           // [3][32][256]
  float* stats = uvec + (size_t)3 * 32 * 256;          // [32][256][2]

  colsum_partial_q<<<dim3(16, 32), 256, 0, stream>>>(q, part);
  colsum_reduce_q<<<32, 256, 0, stream>>>(part, svec);
  gram_mfma<<<512, 256, 0, stream>>>(k, v, Gbuf, svec);
  smallvec<<<32, 256, 0, stream>>>(Wq, bq, Wk, Wv, svec, uvec);
  gemm_pass1<<<dim3(16, 2, 32), 256, 0, stream>>>(Wk, Gbuf, Tbuf);
  gemm_pass2<<<dim3(16, 2, 32), 256, 0, stream>>>(Tbuf, Wk, Wv, Sbuf);
  rank1<<<dim3(256, 2, 32), 256, 0, stream>>>(Sbuf, uvec, bk, bv);
  gj_solve<<<32, 1024, 0, stream>>>(Sbuf);
  rowstats<<<32, 256, 0, stream>>>(Sbuf, stats);
  final_h<<<32, 256, 0, stream>>>(Sbuf, stats, uvec, out);
}

// Round 6
// 574.558 us; speedup vs baseline: 12.8021x; 1.0915x over previous
//
#include <hip/hip_runtime.h>
#include <math.h>

#define FDIM 4096
#define DDIM 256
#define ALPHA_R 0.001f

typedef __attribute__((ext_vector_type(8))) short short8;
typedef __attribute__((ext_vector_type(4))) float f32x4;

__device__ __forceinline__ unsigned cvt_pk_bf16(float lo_e, float hi_e) {
  unsigned r;
  asm("v_cvt_pk_bf16_f32 %0, %1, %2" : "=v"(r) : "v"(lo_e), "v"(hi_e));
  return r;
}

// ---------------- column sums for q only (float4 loads) ----------------
__global__ void colsum_partial_q(const float* __restrict__ q,
                                 float* __restrict__ part) {
  int chunk = blockIdx.x;   // 16
  int b     = blockIdx.y;   // 32
  int tid = threadIdx.x;
  int rg = tid >> 6, dq = tid & 63;
  const float* p = q + ((size_t)b * FDIM + chunk * 256 + rg) * DDIM + dq * 4;
  float4 s = make_float4(0.f, 0.f, 0.f, 0.f);
  for (int i = 0; i < 64; ++i) {
    float4 t = *(const float4*)(p + (size_t)i * 4 * DDIM);
    s.x += t.x; s.y += t.y; s.z += t.z; s.w += t.w;
  }
  __shared__ __align__(16) float red[4][64][4];
  *(float4*)&red[rg][dq][0] = s;
  __syncthreads();
  if (rg == 0) {
    float4 a0 = *(float4*)&red[0][dq][0];
    float4 a1 = *(float4*)&red[1][dq][0];
    float4 a2 = *(float4*)&red[2][dq][0];
    float4 a3 = *(float4*)&red[3][dq][0];
    float4 t = make_float4(a0.x + a1.x + a2.x + a3.x, a0.y + a1.y + a2.y + a3.y,
                           a0.z + a1.z + a2.z + a3.z, a0.w + a1.w + a2.w + a3.w);
    *(float4*)(part + ((size_t)chunk * 32 + b) * DDIM + dq * 4) = t;
  }
}

__global__ void colsum_reduce_q(const float* __restrict__ part,
                                float* __restrict__ svec) {
  int b = blockIdx.x; int d = threadIdx.x;
  float s = 0.f;
  for (int c = 0; c < 16; ++c) s += part[((size_t)c * 32 + b) * DDIM + d];
  svec[(size_t)b * DDIM + d] = s;   // svec[0][b][d]
}

// ---------------- MFMA Gram: G[b][0]=k^T k, G[b][1]=k^T v (bf16 hi/lo, 3-term)
__global__ __launch_bounds__(256) void gram_mfma(const float* __restrict__ kg,
                                                 const float* __restrict__ vg,
                                                 float* __restrict__ G,
                                                 float* __restrict__ svec) {
  int flat = blockIdx.x;            // 512
  int xcd = flat & 7, s = flat >> 3;
  int b = xcd * 4 + (s >> 4);       // 4 batches per XCD
  int tile = s & 15;
  int tm = tile >> 2, tn = tile & 3;
  int mBase = tm * 64, nBase = tn * 64;
  const float* Kb = kg + (size_t)b * FDIM * DDIM;
  const float* Vb = vg + (size_t)b * FDIM * DDIM;

  __shared__ __align__(16) unsigned short Ah[64][40], Al[64][40];
  __shared__ __align__(16) unsigned short Bh[64][40], Bl[64][40];
  __shared__ __align__(16) unsigned short Ch[64][40], Cl[64][40];
  __shared__ float sred[4][68];

  int tid = threadIdx.x;
  int w = tid >> 6, lane = tid & 63;
  int wr = w >> 1, wc = w & 1;
  int lrow = lane & 15;
  int kof = (lane >> 4) * 8;        // ushort col of fragment

  const float* pA = Kb + mBase + lane;
  const float* pB = Kb + nBase + lane;
  const float* pC = Vb + nBase + lane;

  bool doK = (tn == 0), doV = (tm == 0);
  float sK = 0.f, sV = 0.f;

  float xa[8], xb[8], xc[8];
  auto loadIter = [&](int it) {
    int f = it * 32 + w * 8;
#pragma unroll
    for (int j = 0; j < 8; ++j) {
      xa[j] = pA[(size_t)(f + j) * DDIM];
      xb[j] = pB[(size_t)(f + j) * DDIM];
      xc[j] = pC[(size_t)(f + j) * DDIM];
    }
  };
  auto stash = [&](const float* x, unsigned short (*H)[40], unsigned short (*L)[40]) {
    unsigned h0 = cvt_pk_bf16(x[0], x[1]);
    unsigned h1 = cvt_pk_bf16(x[2], x[3]);
    unsigned h2 = cvt_pk_bf16(x[4], x[5]);
    unsigned h3 = cvt_pk_bf16(x[6], x[7]);
    unsigned l0 = cvt_pk_bf16(x[0] - __uint_as_float(h0 << 16),
                              x[1] - __uint_as_float(h0 & 0xFFFF0000u));
    unsigned l1 = cvt_pk_bf16(x[2] - __uint_as_float(h1 << 16),
                              x[3] - __uint_as_float(h1 & 0xFFFF0000u));
    unsigned l2 = cvt_pk_bf16(x[4] - __uint_as_float(h2 << 16),
                              x[5] - __uint_as_float(h2 & 0xFFFF0000u));
    unsigned l3 = cvt_pk_bf16(x[6] - __uint_as_float(h3 << 16),
                              x[7] - __uint_as_float(h3 & 0xFFFF0000u));
    *(uint4*)&H[lane][w * 8] = make_uint4(h0, h1, h2, h3);
    *(uint4*)&L[lane][w * 8] = make_uint4(l0, l1, l2, l3);
  };

  f32x4 acc0[2][2], acc1[2][2];
#pragma unroll
  for (int mt = 0; mt < 2; ++mt)
#pragma unroll
    for (int nt = 0; nt < 2; ++nt) {
      acc0[mt][nt] = (f32x4){0.f, 0.f, 0.f, 0.f};
      acc1[mt][nt] = (f32x4){0.f, 0.f, 0.f, 0.f};
    }

  loadIter(0);
  for (int it = 0; it < 128; ++it) {
    __syncthreads();
    stash(xa, Ah, Al);
    stash(xb, Bh, Bl);
    stash(xc, Ch, Cl);
    if (doK) sK += ((xa[0] + xa[1]) + (xa[2] + xa[3])) + ((xa[4] + xa[5]) + (xa[6] + xa[7]));
    if (doV) sV += ((xc[0] + xc[1]) + (xc[2] + xc[3])) + ((xc[4] + xc[5]) + (xc[6] + xc[7]));
    __syncthreads();
    if (it < 127) loadIter(it + 1);

    short8 bh[2], bl[2], ch[2], cl[2];
#pragma unroll
    for (int nt = 0; nt < 2; ++nt) {
      int rB = wc * 32 + nt * 16 + lrow;
      bh[nt] = *(const short8*)&Bh[rB][kof];
      bl[nt] = *(const short8*)&Bl[rB][kof];
      ch[nt] = *(const short8*)&Ch[rB][kof];
      cl[nt] = *(const short8*)&Cl[rB][kof];
    }
    __builtin_amdgcn_s_setprio(1);
#pragma unroll
    for (int mt = 0; mt < 2; ++mt) {
      int rA = wr * 32 + mt * 16 + lrow;
      short8 ah = *(const short8*)&Ah[rA][kof];
      short8 al = *(const short8*)&Al[rA][kof];
#pragma unroll
      for (int nt = 0; nt < 2; ++nt) {
        f32x4 t = acc0[mt][nt];
        t = __builtin_amdgcn_mfma_f32_16x16x32_bf16(ah, bh[nt], t, 0, 0, 0);
        t = __builtin_amdgcn_mfma_f32_16x16x32_bf16(ah, bl[nt], t, 0, 0, 0);
        t = __builtin_amdgcn_mfma_f32_16x16x32_bf16(al, bh[nt], t, 0, 0, 0);
        acc0[mt][nt] = t;
        f32x4 u = acc1[mt][nt];
        u = __builtin_amdgcn_mfma_f32_16x16x32_bf16(ah, ch[nt], u, 0, 0, 0);
        u = __builtin_amdgcn_mfma_f32_16x16x32_bf16(ah, cl[nt], u, 0, 0, 0);
        u = __builtin_amdgcn_mfma_f32_16x16x32_bf16(al, ch[nt], u, 0, 0, 0);
        acc1[mt][nt] = u;
      }
    }
    __builtin_amdgcn_s_setprio(0);
  }

  float* G0 = G + ((size_t)b * 2) * 65536;
  float* G1 = G0 + 65536;
#pragma unroll
  for (int mt = 0; mt < 2; ++mt)
#pragma unroll
    for (int nt = 0; nt < 2; ++nt)
#pragma unroll
      for (int r = 0; r < 4; ++r) {
        int row = mBase + wr * 32 + mt * 16 + (lane >> 4) * 4 + r;
        int col = nBase + wc * 32 + nt * 16 + (lane & 15);
        G0[(size_t)row * DDIM + col] = acc0[mt][nt][r];
        G1[(size_t)row * DDIM + col] = acc1[mt][nt][r];
      }

  if (doK) {
    __syncthreads();
    sred[w][lane] = sK;
    __syncthreads();
    if (tid < 64) {
      float t = sred[0][tid] + sred[1][tid] + sred[2][tid] + sred[3][tid];
      svec[(size_t)1 * 32 * 256 + (size_t)b * 256 + mBase + tid] = t;
    }
  }
  if (doV) {
    __syncthreads();
    sred[w][lane] = sV;
    __syncthreads();
    if (tid < 64) {
      float t = sred[0][tid] + sred[1][tid] + sred[2][tid] + sred[3][tid];
      svec[(size_t)2 * 32 * 256 + (size_t)b * 256 + nBase + tid] = t;
    }
  }
}

// ---------------- small vectors: uk=Wk sk, uv=Wv sv, qsum=Wq sq + F bq ------
__global__ void smallvec(const float* __restrict__ Wq, const float* __restrict__ bq,
                         const float* __restrict__ Wk, const float* __restrict__ Wv,
                         const float* __restrict__ svec, float* __restrict__ uvec) {
  int b = blockIdx.x; int d = threadIdx.x;
  __shared__ float sq[256], sk[256], sv[256];
  sq[d] = svec[((size_t)0 * 32 + b) * DDIM + d];
  sk[d] = svec[((size_t)1 * 32 + b) * DDIM + d];
  sv[d] = svec[((size_t)2 * 32 + b) * DDIM + d];
  __syncthreads();
  float uk = 0.f, uv = 0.f, uq = 0.f;
  for (int j = 0; j < 256; j += 4) {
    float4 wk4 = *(const float4*)(Wk + (size_t)d * DDIM + j);
    float4 wv4 = *(const float4*)(Wv + (size_t)d * DDIM + j);
    float4 wq4 = *(const float4*)(Wq + (size_t)d * DDIM + j);
    uk += wk4.x * sk[j] + wk4.y * sk[j + 1] + wk4.z * sk[j + 2] + wk4.w * sk[j + 3];
    uv += wv4.x * sv[j] + wv4.y * sv[j + 1] + wv4.z * sv[j + 2] + wv4.w * sv[j + 3];
    uq += wq4.x * sq[j] + wq4.y * sq[j + 1] + wq4.z * sq[j + 2] + wq4.w * sq[j + 3];
  }
  uvec[((size_t)0 * 32 + b) * DDIM + d] = uk;
  uvec[((size_t)1 * 32 + b) * DDIM + d] = uv;
  uvec[((size_t)2 * 32 + b) * DDIM + d] = uq + 4096.f * bq[d];
}

// ---------------- T[b][w] = Wk @ G[b][w]  (nn GEMM) ----------------
__global__ __launch_bounds__(256) void gemm_pass1(const float* __restrict__ Wk,
                                                  const float* __restrict__ G,
                                                  float* __restrict__ T) {
  int tile = blockIdx.x, w = blockIdx.y, b = blockIdx.z;
  int tm = tile >> 2, tn = tile & 3;
  const float* A = Wk;
  const float* B = G + ((size_t)b * 2 + w) * 65536;
  float* C = T + ((size_t)b * 2 + w) * 65536;
  __shared__ __align__(16) float As[16][64];
  __shared__ __align__(16) float Bs[16][64];
  int tid = threadIdx.x;
  int ty = tid >> 4, tx = tid & 15;
  int am = tid & 63, ak4 = tid >> 6;
  int brow = tid >> 4, bcol4 = tid & 15;
  int mBase = tm * 64, nBase = tn * 64;
  float acc[4][4];
#pragma unroll
  for (int i = 0; i < 4; i++)
#pragma unroll
    for (int j = 0; j < 4; j++) acc[i][j] = 0.f;
  for (int k0 = 0; k0 < 256; k0 += 16) {
    float4 a = *(const float4*)(A + (size_t)(mBase + am) * DDIM + k0 + ak4 * 4);
    float4 bb = *(const float4*)(B + (size_t)(k0 + brow) * DDIM + nBase + bcol4 * 4);
    __syncthreads();
    As[ak4 * 4 + 0][am] = a.x; As[ak4 * 4 + 1][am] = a.y;
    As[ak4 * 4 + 2][am] = a.z; As[ak4 * 4 + 3][am] = a.w;
    *(float4*)&Bs[brow][bcol4 * 4] = bb;
    __syncthreads();
#pragma unroll
    for (int kstep = 0; kstep < 16; ++kstep) {
      float4 a4 = *(const float4*)&As[kstep][ty * 4];
      float4 b4 = *(const float4*)&Bs[kstep][tx * 4];
      float av[4] = {a4.x, a4.y, a4.z, a4.w};
      float bvv[4] = {b4.x, b4.y, b4.z, b4.w};
#pragma unroll
      for (int i = 0; i < 4; i++)
#pragma unroll
        for (int j = 0; j < 4; j++)
          acc[i][j] = fmaf(av[i], bvv[j], acc[i][j]);
    }
  }
#pragma unroll
  for (int i = 0; i < 4; i++) {
    float4 o = make_float4(acc[i][0], acc[i][1], acc[i][2], acc[i][3]);
    *(float4*)(C + (size_t)(mBase + ty * 4 + i) * DDIM + nBase + tx * 4) = o;
  }
}

// ---------------- S[b][w] = T[b][w] @ W^T  (nt GEMM) ----------------
__global__ __launch_bounds__(256) void gemm_pass2(const float* __restrict__ T,
                                                  const float* __restrict__ Wk,
                                                  const float* __restrict__ Wv,
                                                  float* __restrict__ S) {
  int tile = blockIdx.x, w = blockIdx.y, b = blockIdx.z;
  int tm = tile >> 2, tn = tile & 3;
  const float* A = T + ((size_t)b * 2 + w) * 65536;
  const float* W = w ? Wv : Wk;
  float* C = S + ((size_t)b * 2 + w) * 65536;
  __shared__ __align__(16) float As[16][64];
  __shared__ __align__(16) float Bs[16][64];
  int tid = threadIdx.x;
  int ty = tid >> 4, tx = tid & 15;
  int am = tid & 63, ak4 = tid >> 6;
  int mBase = tm * 64, nBase = tn * 64;
  float acc[4][4];
#pragma unroll
  for (int i = 0; i < 4; i++)
#pragma unroll
    for (int j = 0; j < 4; j++) acc[i][j] = 0.f;
  for (int k0 = 0; k0 < 256; k0 += 16) {
    float4 a = *(const float4*)(A + (size_t)(mBase + am) * DDIM + k0 + ak4 * 4);
    float4 bb = *(const float4*)(W + (size_t)(nBase + am) * DDIM + k0 + ak4 * 4);
    __syncthreads();
    As[ak4 * 4 + 0][am] = a.x; As[ak4 * 4 + 1][am] = a.y;
    As[ak4 * 4 + 2][am] = a.z; As[ak4 * 4 + 3][am] = a.w;
    Bs[ak4 * 4 + 0][am] = bb.x; Bs[ak4 * 4 + 1][am] = bb.y;
    Bs[ak4 * 4 + 2][am] = bb.z; Bs[ak4 * 4 + 3][am] = bb.w;
    __syncthreads();
#pragma unroll
    for (int kstep = 0; kstep < 16; ++kstep) {
      float4 a4 = *(const float4*)&As[kstep][ty * 4];
      float4 b4 = *(const float4*)&Bs[kstep][tx * 4];
      float av[4] = {a4.x, a4.y, a4.z, a4.w};
      float bvv[4] = {b4.x, b4.y, b4.z, b4.w};
#pragma unroll
      for (int i = 0; i < 4; i++)
#pragma unroll
        for (int j = 0; j < 4; j++)
          acc[i][j] = fmaf(av[i], bvv[j], acc[i][j]);
    }
  }
#pragma unroll
  for (int i = 0; i < 4; i++) {
    float4 o = make_float4(acc[i][0], acc[i][1], acc[i][2], acc[i][3]);
    *(float4*)(C + (size_t)(mBase + ty * 4 + i) * DDIM + nBase + tx * 4) = o;
  }
}

// ---------------- rank-1 bias terms + alpha*I ----------------
__global__ void rank1(float* __restrict__ S, const float* __restrict__ uvec,
                      const float* __restrict__ bk, const float* __restrict__ bv) {
  int d = blockIdx.x, w = blockIdx.y, b = blockIdx.z;
  int e = threadIdx.x;
  float* row = S + (((size_t)b * 2 + w) * DDIM + d) * DDIM;
  float ukd = uvec[((size_t)0 * 32 + b) * DDIM + d];
  float bkd = bk[d];
  if (w == 0) {
    float uke = uvec[((size_t)0 * 32 + b) * DDIM + e];
    float add = ukd * bk[e] + bkd * uke + 4096.f * bkd * bk[e] + ((d == e) ? ALPHA_R : 0.f);
    row[e] += add;
  } else {
    float uve = uvec[((size_t)1 * 32 + b) * DDIM + e];
    float add = ukd * bv[e] + bkd * uve + 4096.f * bkd * bv[e];
    row[e] += add;
  }
}

// ---------------- gj_factor: factor A, store Mt panels, update trailing A ---
// Single-barrier pivot loop (double-buffered prow/fac). B-updates deferred.
__global__ __launch_bounds__(1024, 4) void gj_factor(float* __restrict__ Sb,
                                                     float* __restrict__ Mtg) {
  int b = blockIdx.x;
  float* A = Sb + (size_t)b * 2 * 65536;
  int tid = threadIdx.x;
  int r = tid >> 2;
  int q = tid & 3;

  __shared__ __align__(16) float Mt[64][264];
  __shared__ __align__(16) float Sst[64][200];
  __shared__ __align__(16) float prow[2][64];
  __shared__ float fac[2][256];

  for (int pg = 0; pg < 4; ++pg) {
    float x[16];
    {
      const float* Ar = A + (size_t)r * 256 + pg * 64 + q * 16;
#pragma unroll
      for (int m = 0; m < 4; ++m) {
        float4 t = *(const float4*)(Ar + m * 4);
        x[m * 4 + 0] = t.x; x[m * 4 + 1] = t.y;
        x[m * 4 + 2] = t.z; x[m * 4 + 3] = t.w;
      }
    }
    // pre-publish pivot 0's row and column
    if (r == pg * 64) {
      *(float4*)&prow[0][q * 16 + 0]  = make_float4(x[0], x[1], x[2], x[3]);
      *(float4*)&prow[0][q * 16 + 4]  = make_float4(x[4], x[5], x[6], x[7]);
      *(float4*)&prow[0][q * 16 + 8]  = make_float4(x[8], x[9], x[10], x[11]);
      *(float4*)&prow[0][q * 16 + 12] = make_float4(x[12], x[13], x[14], x[15]);
    }
    if (q == 0) fac[0][r] = x[0];
    __syncthreads();

#pragma unroll
    for (int jo = 0; jo < 4; ++jo) {
#pragma unroll
      for (int ji = 0; ji < 16; ++ji) {
        const int j = jo * 16 + ji;
        const int p = pg * 64 + j;
        const int buf = j & 1, nb = buf ^ 1;
        float piv = fac[buf][p];
        float ip = 1.0f / piv;
        float g = fac[buf][r] * ip;
        bool diag = (r == p);
#pragma unroll
        for (int m = 0; m < 16; ++m) {
          float pv = prow[buf][q * 16 + m];
          x[m] = diag ? pv * ip : fmaf(-g, pv, x[m]);
        }
        if (q == jo) x[ji] = diag ? ip : (0.f - g);
        if (j < 63) {
          const int jn = j + 1;
          if (r == pg * 64 + jn) {
            *(float4*)&prow[nb][q * 16 + 0]  = make_float4(x[0], x[1], x[2], x[3]);
            *(float4*)&prow[nb][q * 16 + 4]  = make_float4(x[4], x[5], x[6], x[7]);
            *(float4*)&prow[nb][q * 16 + 8]  = make_float4(x[8], x[9], x[10], x[11]);
            *(float4*)&prow[nb][q * 16 + 12] = make_float4(x[12], x[13], x[14], x[15]);
          }
          if (q == (jn >> 4)) fac[nb][r] = x[jn & 15];
        }
        __syncthreads();
      }
    }
    // dump M transposed to LDS: Mt[j][r]
#pragma unroll
    for (int m = 0; m < 16; ++m) Mt[q * 16 + m][r] = x[m];
    __syncthreads();

    // dump Mt to global for the deferred B apply
    {
      int j = tid >> 4, rseg = (tid & 15) * 16;
      float* dst = Mtg + (((size_t)b * 4 + pg) * 64 + j) * 256 + rseg;
#pragma unroll
      for (int m = 0; m < 4; ++m) {
        float4 t = make_float4(Mt[j][rseg + m * 4 + 0], Mt[j][rseg + m * 4 + 1],
                               Mt[j][rseg + m * 4 + 2], Mt[j][rseg + m * 4 + 3]);
        *(float4*)(dst + m * 4) = t;
      }
    }

    // trailing A update only (cols > panel)
    int W = (3 - pg) * 64;
    if (W > 0) {
      int c_off = (pg + 1) * 64;
      {
        int cpt = W >> 4;                    // 12, 8, 4
        int jr = tid >> 4, tc = tid & 15;
        const float* src = A + (size_t)(pg * 64 + jr) * 256 + c_off + tc * cpt;
        for (int m = 0; m < cpt; m += 4) {
          float4 t = *(const float4*)(src + m);
          *(float4*)&Sst[jr][tc * cpt + m] = t;
        }
      }
      __syncthreads();
      int colTiles = W >> 3;
      int rt = tid / colTiles;
      int ctile = tid - rt * colTiles;
      if (rt < 32) {
        int r0 = rt * 8, c0 = ctile * 8;
        float acc[8][8];
#pragma unroll
        for (int i = 0; i < 8; ++i)
#pragma unroll
          for (int j2 = 0; j2 < 8; ++j2) acc[i][j2] = 0.f;
        for (int j = 0; j < 64; ++j) {
          float4 m0 = *(const float4*)&Mt[j][r0];
          float4 m1 = *(const float4*)&Mt[j][r0 + 4];
          float4 s0 = *(const float4*)&Sst[j][c0];
          float4 s1 = *(const float4*)&Sst[j][c0 + 4];
          float mv[8] = {m0.x, m0.y, m0.z, m0.w, m1.x, m1.y, m1.z, m1.w};
          float sv[8] = {s0.x, s0.y, s0.z, s0.w, s1.x, s1.y, s1.z, s1.w};
#pragma unroll
          for (int i = 0; i < 8; ++i)
#pragma unroll
            for (int j2 = 0; j2 < 8; ++j2)
              acc[i][j2] = fmaf(mv[i], sv[j2], acc[i][j2]);
        }
#pragma unroll
        for (int ii = 0; ii < 8; ++ii) {
          int row = r0 + ii;
          bool inPanel = ((row >> 6) == pg);
          float* dst = A + (size_t)row * 256 + c_off + c0;
          float4 o0 = make_float4(acc[ii][0], acc[ii][1], acc[ii][2], acc[ii][3]);
          float4 o1 = make_float4(acc[ii][4], acc[ii][5], acc[ii][6], acc[ii][7]);
          if (!inPanel) {
            float4 a0 = *(const float4*)(dst);
            float4 a1 = *(const float4*)(dst + 4);
            o0.x += a0.x; o0.y += a0.y; o0.z += a0.z; o0.w += a0.w;
            o1.x += a1.x; o1.y += a1.y; o1.z += a1.z; o1.w += a1.w;
          }
          *(float4*)(dst) = o0;
          *(float4*)(dst + 4) = o1;
        }
      }
      __syncthreads();
    }
  }
}

// ---------------- gj_apply: B <- E4 E3 E2 E1 B, 8 col-stripes x 32 batches --
__global__ __launch_bounds__(256) void gj_apply(float* __restrict__ Sb,
                                                const float* __restrict__ Mtg) {
  int blk = blockIdx.x;             // 256
  int b = blk >> 3;
  int cbase = (blk & 7) * 32;
  float* Bm = Sb + ((size_t)b * 2 + 1) * 65536;
  int tid = threadIdx.x;
  int rt = tid >> 3;                // 0..31, owns rows rt*8..rt*8+7
  int ct = tid & 7;                 // cols cbase + ct*4 .. +4

  __shared__ __align__(16) float Mt[64][260];
  __shared__ __align__(8) float Bp[64][34];

  float4 breg[8];
#pragma unroll
  for (int i = 0; i < 8; ++i)
    breg[i] = *(const float4*)(Bm + (size_t)(rt * 8 + i) * 256 + cbase + ct * 4);

  for (int pg = 0; pg < 4; ++pg) {
    __syncthreads();
    // stage Mt[pg] from global
    {
      int j = tid >> 2, seg = (tid & 3) * 64;
      const float* src = Mtg + (((size_t)b * 4 + pg) * 64 + j) * 256 + seg;
#pragma unroll
      for (int m = 0; m < 16; ++m) {
        float4 t = *(const float4*)(src + m * 4);
        *(float4*)&Mt[j][seg + m * 4] = t;
      }
    }
    // stage panel rows of B
    if (rt >= pg * 8 && rt < (pg + 1) * 8) {
#pragma unroll
      for (int i = 0; i < 8; ++i) {
        int j = (rt - pg * 8) * 8 + i;
        *(float2*)&Bp[j][ct * 4]     = make_float2(breg[i].x, breg[i].y);
        *(float2*)&Bp[j][ct * 4 + 2] = make_float2(breg[i].z, breg[i].w);
      }
    }
    __syncthreads();

    float acc[8][4];
#pragma unroll
    for (int i = 0; i < 8; ++i)
#pragma unroll
      for (int c = 0; c < 4; ++c) acc[i][c] = 0.f;
#pragma unroll 4
    for (int j = 0; j < 64; ++j) {
      float4 m0 = *(const float4*)&Mt[j][rt * 8];
      float4 m1 = *(const float4*)&Mt[j][rt * 8 + 4];
      float2 b0 = *(const float2*)&Bp[j][ct * 4];
      float2 b1 = *(const float2*)&Bp[j][ct * 4 + 2];
      float mv[8] = {m0.x, m0.y, m0.z, m0.w, m1.x, m1.y, m1.z, m1.w};
      float bv4[4] = {b0.x, b0.y, b1.x, b1.y};
#pragma unroll
      for (int i = 0; i < 8; ++i)
#pragma unroll
        for (int c = 0; c < 4; ++c)
          acc[i][c] = fmaf(mv[i], bv4[c], acc[i][c]);
    }
    bool inPanel = ((rt >> 3) == pg);
#pragma unroll
    for (int i = 0; i < 8; ++i) {
      if (inPanel) {
        breg[i] = make_float4(acc[i][0], acc[i][1], acc[i][2], acc[i][3]);
      } else {
        breg[i].x += acc[i][0]; breg[i].y += acc[i][1];
        breg[i].z += acc[i][2]; breg[i].w += acc[i][3];
      }
    }
  }

#pragma unroll
  for (int i = 0; i < 8; ++i)
    *(float4*)(Bm + (size_t)(rt * 8 + i) * 256 + cbase + ct * 4) = breg[i];
}

// ---------------- row softmax stats (max, sumexp) over X rows ----------------
__global__ void rowstats(const float* __restrict__ S, float* __restrict__ stats) {
  int b = blockIdx.x;
  const float* X = S + ((size_t)b * 2 + 1) * 65536;
  int tid = threadIdx.x; int lane = tid & 63; int wv = tid >> 6;
  for (int rr = 0; rr < 64; ++rr) {
    int row = rr * 4 + wv;
    float x0 = X[row * 256 + lane];
    float x1 = X[row * 256 + lane + 64];
    float x2 = X[row * 256 + lane + 128];
    float x3 = X[row * 256 + lane + 192];
    float m = fmaxf(fmaxf(x0, x1), fmaxf(x2, x3));
    for (int o = 32; o > 0; o >>= 1) m = fmaxf(m, __shfl_xor(m, o, 64));
    float s = expf(x0 - m) + expf(x1 - m) + expf(x2 - m) + expf(x3 - m);
    for (int o = 32; o > 0; o >>= 1) s += __shfl_xor(s, o, 64);
    if (lane == 0) {
      stats[((size_t)b * 256 + row) * 2 + 0] = m;
      stats[((size_t)b * 256 + row) * 2 + 1] = s;
    }
  }
}

// ---------------- h[b,e] = sum_d qsum[b,d] * softmax(X[b,d,:])[e] ----------
__global__ void final_h(const float* __restrict__ S, const float* __restrict__ stats,
                        const float* __restrict__ uvec, float* __restrict__ out) {
  int b = blockIdx.x; int e = threadIdx.x;
  const float* X = S + ((size_t)b * 2 + 1) * 65536;
  const float* qs = uvec + ((size_t)2 * 32 + b) * DDIM;
  float acc = 0.f;
  for (int d = 0; d < 256; ++d) {
    float m = stats[((size_t)b * 256 + d) * 2 + 0];
    float s = stats[((size_t)b * 256 + d) * 2 + 1];
    acc += qs[d] * expf(X[d * 256 + e] - m) / s;
  }
  out[(size_t)b * 256 + e] = acc;
}

extern "C" void kernel_launch(void* const* d_in, const int* in_sizes, int n_in,
                              void* d_out, int out_size, void* d_ws, size_t ws_size,
                              hipStream_t stream) {
  const float* q  = (const float*)d_in[0];
  const float* k  = (const float*)d_in[1];
  const float* v  = (const float*)d_in[2];
  const float* Wq = (const float*)d_in[3];
  const float* bq = (const float*)d_in[4];
  const float* Wk = (const float*)d_in[5];
  const float* bk = (const float*)d_in[6];
  const float* Wv = (const float*)d_in[7];
  const float* bv = (const float*)d_in[8];
  float* out = (float*)d_out;

  float* ws   = (float*)d_ws;
  float* Gbuf = ws;                                    // [32][2][256][256]; reused as Mtg [32][4][64][256]
  float* Tbuf = Gbuf + (size_t)32 * 2 * 65536;         // [32][2][256][256]
  float* Sbuf = Tbuf + (size_t)32 * 2 * 65536;         // [32][2][256][256] (A, B->X)
  float* part = Sbuf + (size_t)32 * 2 * 65536;         // [16][32][256] (q partials)
  float* svec = part + (size_t)16 * 3 * 32 * 256;      // [3][32][256]
  float* uvec = svec + (size_t)3 * 32 * 256;           // [3][32][256]
  float* stats = uvec + (size_t)3 * 32 * 256;          // [32][256][2]

  colsum_partial_q<<<dim3(16, 32), 256, 0, stream>>>(q, part);
  colsum_reduce_q<<<32, 256, 0, stream>>>(part, svec);
  gram_mfma<<<512, 256, 0, stream>>>(k, v, Gbuf, svec);
  smallvec<<<32, 256, 0, stream>>>(Wq, bq, Wk, Wv, svec, uvec);
  gemm_pass1<<<dim3(16, 2, 32), 256, 0, stream>>>(Wk, Gbuf, Tbuf);
  gemm_pass2<<<dim3(16, 2, 32), 256, 0, stream>>>(Tbuf, Wk, Wv, Sbuf);
  rank1<<<dim3(256, 2, 32), 256, 0, stream>>>(Sbuf, uvec, bk, bv);
  gj_factor<<<32, 1024, 0, stream>>>(Sbuf, Gbuf);
  gj_apply<<<256, 256, 0, stream>>>(Sbuf, Gbuf);
  rowstats<<<32, 256, 0, stream>>>(Sbuf, stats);
  final_h<<<32, 256, 0, stream>>>(Sbuf, stats, uvec, out);
}